// Round 12
// baseline (622.655 us; speedup 1.0000x reference)
//
#include <hip/hip_runtime.h>
#include <math.h>

#define NB 4
#define NN 4096
#define NC 128
#define NROWS (NB*NN)
#define SCALE_F 0.08838834764831845f   // 1/sqrt(128)

using bf16x8 = __attribute__((ext_vector_type(8))) short;
using f32x4  = __attribute__((ext_vector_type(4))) float;

__device__ __forceinline__ float rl_f(float x, int l) {
    return __int_as_float(__builtin_amdgcn_readlane(__float_as_int(x), l));
}
__device__ __forceinline__ ushort f2bf(float x) {          // fp32 -> bf16 RNE
    unsigned u = __float_as_uint(x);
    return (ushort)((u + 0x7FFF + ((u >> 16) & 1)) >> 16);
}
__device__ __forceinline__ float bf2f(ushort b) { return __uint_as_float(((unsigned)b) << 16); }

// monotone key: (order-preserving float bits) << 32 | index  — lex (value, idx) asc
__device__ __forceinline__ unsigned long long mkkey(float d2, int idx) {
    unsigned u = __float_as_uint(d2);
    u ^= ((unsigned)((int)u >> 31)) | 0x80000000u;
    return ((unsigned long long)u << 32) | (unsigned)idx;
}

// ---- 16-deep sorted (ascending) float register lists (knn1) ----
#define DECL16V \
    float v0=INFINITY,v1=INFINITY,v2=INFINITY,v3=INFINITY,v4=INFINITY,v5=INFINITY,v6=INFINITY,v7=INFINITY, \
          v8=INFINITY,v9=INFINITY,v10=INFINITY,v11=INFINITY,v12=INFINITY,v13=INFINITY,v14=INFINITY,v15=INFINITY;

#define INSERT16V(dv) do { float d_=(dv); \
    bool m0=d_<v0,m1=d_<v1,m2=d_<v2,m3=d_<v3,m4=d_<v4,m5=d_<v5,m6=d_<v6,m7=d_<v7, \
         m8=d_<v8,m9=d_<v9,m10=d_<v10,m11=d_<v11,m12=d_<v12,m13=d_<v13,m14=d_<v14,m15=d_<v15; \
    v15=m14?v14:(m15?d_:v15); v14=m13?v13:(m14?d_:v14); v13=m12?v12:(m13?d_:v13); v12=m11?v11:(m12?d_:v12); \
    v11=m10?v10:(m11?d_:v11); v10=m9?v9:(m10?d_:v10); v9 =m8?v8:(m9?d_:v9);  v8 =m7?v7:(m8?d_:v8); \
    v7 =m6?v6:(m7?d_:v7);   v6 =m5?v5:(m6?d_:v6);   v5 =m4?v4:(m5?d_:v5);  v4 =m3?v3:(m4?d_:v4); \
    v3 =m2?v2:(m3?d_:v3);   v2 =m1?v1:(m2?d_:v2);   v1 =m0?v0:(m1?d_:v1);  v0 =m0?d_:v0; } while(0)

#define POP16V(p) do { bool p_=(p); \
    v0=p_?v1:v0; v1=p_?v2:v1; v2=p_?v3:v2; v3=p_?v4:v3; v4=p_?v5:v4; v5=p_?v6:v5; v6=p_?v7:v6; v7=p_?v8:v7; \
    v8=p_?v9:v8; v9=p_?v10:v9; v10=p_?v11:v10; v11=p_?v12:v11; v12=p_?v13:v12; v13=p_?v14:v13; v14=p_?v15:v14; \
    v15=p_?INFINITY:v15; } while(0)

// ---- 16-deep sorted (ascending) u64-key register lists (knn2) ----
#define KMAX16 0xFFFFFFFFFFFFFFFFull
#define DECL16K \
    unsigned long long K0=KMAX16,K1=KMAX16,K2=KMAX16,K3=KMAX16,K4=KMAX16,K5=KMAX16,K6=KMAX16,K7=KMAX16, \
                       K8=KMAX16,K9=KMAX16,K10=KMAX16,K11=KMAX16,K12=KMAX16,K13=KMAX16,K14=KMAX16,K15=KMAX16;

#define INSERT16K(kv) do { unsigned long long k_=(kv); \
    bool m0=k_<K0,m1=k_<K1,m2=k_<K2,m3=k_<K3,m4=k_<K4,m5=k_<K5,m6=k_<K6,m7=k_<K7, \
         m8=k_<K8,m9=k_<K9,m10=k_<K10,m11=k_<K11,m12=k_<K12,m13=k_<K13,m14=k_<K14,m15=k_<K15; \
    K15=m14?K14:(m15?k_:K15); K14=m13?K13:(m14?k_:K14); K13=m12?K12:(m13?k_:K13); K12=m11?K11:(m12?k_:K12); \
    K11=m10?K10:(m11?k_:K11); K10=m9?K9:(m10?k_:K10);   K9 =m8?K8:(m9?k_:K9);    K8 =m7?K7:(m8?k_:K8); \
    K7 =m6?K6:(m7?k_:K7);     K6 =m5?K5:(m6?k_:K6);     K5 =m4?K4:(m5?k_:K5);    K4 =m3?K3:(m4?k_:K4); \
    K3 =m2?K2:(m3?k_:K3);     K2 =m1?K1:(m2?k_:K2);     K1 =m0?K0:(m1?k_:K1);    K0 =m0?k_:K0; } while(0)

#define POP16K(p) do { bool p_=(p); \
    K0=p_?K1:K0; K1=p_?K2:K1; K2=p_?K3:K2; K3=p_?K4:K3; K4=p_?K5:K4; K5=p_?K6:K5; K6=p_?K7:K6; K7=p_?K8:K7; \
    K8=p_?K9:K8; K9=p_?K10:K9; K10=p_?K11:K10; K11=p_?K12:K11; K12=p_?K13:K12; K13=p_?K14:K13; K14=p_?K15:K14; \
    K15=p_?KMAX16:K15; } while(0)

// ---------------- tiny weight combos ----------------
__global__ void combo_small(const float* __restrict__ Wk0, const float* __restrict__ Wv0,
                            const float* __restrict__ Wp0, const float* __restrict__ bp0,
                            float* __restrict__ WKP0, float* __restrict__ BK0,
                            float* __restrict__ WVP0, float* __restrict__ BV0)
{
    int task = blockIdx.x * 512 + threadIdx.x;
    if (task >= 1024) return;
    int mat = task >> 9; int rem = task & 511;
    int c = rem >> 2, t = rem & 3;
    const float* W = mat ? Wv0 : Wk0;
    float s = 0.f;
    if (t < 3) {
        for (int d = 0; d < 128; ++d) s = fmaf(W[c*128+d], Wp0[d*3+t], s);
        (mat ? WVP0 : WKP0)[c*3+t] = s;
    } else {
        for (int d = 0; d < 128; ++d) s = fmaf(W[c*128+d], bp0[d], s);
        (mat ? BV0 : BK0)[c] = s;
    }
}

// WKD = Wk1 - Wk1@Wp1 ; MV1 = Wv1@Wp1 ; WVD = Wv1 - MV1 ; BV1 = Wv1@bp1
__global__ void combo_big(const float* __restrict__ Wk1, const float* __restrict__ Wv1,
                          const float* __restrict__ Wp1, const float* __restrict__ bp1,
                          float* __restrict__ WKD, float* __restrict__ MV1,
                          float* __restrict__ WVD, float* __restrict__ BV1)
{
    int task = blockIdx.x * 256 + threadIdx.x;   // grid 129 x 256
    if (task >= 32896) return;
    if (task < 32768) {
        int mat = task >> 14; int rem = task & 16383;
        int c = rem >> 7, tcol = rem & 127;
        const float* W = mat ? Wv1 : Wk1;
        float s = 0.f;
        for (int d = 0; d < 128; ++d) s = fmaf(W[c*128+d], Wp1[d*128+tcol], s);
        if (mat) { MV1[rem] = s; WVD[rem] = Wv1[rem] - s; }
        else     { WKD[rem] = Wk1[rem] - s; }
    } else {
        int c = task - 32768;
        float s = 0.f;
        for (int d = 0; d < 128; ++d) s = fmaf(Wv1[c*128+d], bp1[d], s);
        BV1[c] = s;
    }
}

// split 7 weight matrices (16384 elems each) into contiguous bf16 hi/lo slots
__global__ void split7(const float* __restrict__ W0, const float* __restrict__ W1,
                       const float* __restrict__ W2, const float* __restrict__ W3,
                       const float* __restrict__ W4, const float* __restrict__ W5,
                       const float* __restrict__ W6,
                       ushort* __restrict__ WSH, ushort* __restrict__ WSL)
{
    int y = blockIdx.y;
    const float* W;
    switch (y) {
        case 0: W = W0; break; case 1: W = W1; break; case 2: W = W2; break;
        case 3: W = W3; break; case 4: W = W4; break; case 5: W = W5; break;
        default: W = W6; break;
    }
    int i = blockIdx.x*256 + threadIdx.x;          // grid.x = 64
    float v = W[i];
    ushort h = f2bf(v);
    WSH[y*16384 + i] = h;
    WSL[y*16384 + i] = f2bf(v - bf2f(h));
}

// split fp32 activation matrix into bf16 hi/lo (8 elems/thread)
__global__ void splitx(const float* __restrict__ X, ushort* __restrict__ XH,
                       ushort* __restrict__ XL)
{
    int i = (blockIdx.x*256 + threadIdx.x) * 8;    // grid 1024
    float4 a = *(const float4*)&X[i];
    float4 b = *(const float4*)&X[i+4];
    ushort h0=f2bf(a.x),h1=f2bf(a.y),h2=f2bf(a.z),h3=f2bf(a.w);
    ushort h4=f2bf(b.x),h5=f2bf(b.y),h6=f2bf(b.z),h7=f2bf(b.w);
    uint4 ph;
    ph.x=(unsigned)h0|((unsigned)h1<<16); ph.y=(unsigned)h2|((unsigned)h3<<16);
    ph.z=(unsigned)h4|((unsigned)h5<<16); ph.w=(unsigned)h6|((unsigned)h7<<16);
    *(uint4*)&XH[i] = ph;
    ushort l0=f2bf(a.x-bf2f(h0)),l1=f2bf(a.y-bf2f(h1)),l2=f2bf(a.z-bf2f(h2)),l3=f2bf(a.w-bf2f(h3));
    ushort l4=f2bf(b.x-bf2f(h4)),l5=f2bf(b.y-bf2f(h5)),l6=f2bf(b.z-bf2f(h6)),l7=f2bf(b.w-bf2f(h7));
    uint4 pl;
    pl.x=(unsigned)l0|((unsigned)l1<<16); pl.y=(unsigned)l2|((unsigned)l3<<16);
    pl.z=(unsigned)l4|((unsigned)l5<<16); pl.w=(unsigned)l6|((unsigned)l7<<16);
    *(uint4*)&XL[i] = pl;
}

__global__ void srcproj(const float* __restrict__ src, const float* __restrict__ WKP0,
                        const float* __restrict__ WVP0,
                        float* __restrict__ srcKp, float* __restrict__ srcVp)
{
    int gid = blockIdx.x * 256 + threadIdx.x;
    int i = gid >> 7, c = gid & 127;
    float s0 = src[i*3+0], s1 = src[i*3+1], s2 = src[i*3+2];
    srcKp[gid] = fmaf(s0, WKP0[c*3+0], fmaf(s1, WKP0[c*3+1], s2*WKP0[c*3+2]));
    srcVp[gid] = fmaf(s0, WVP0[c*3+0], fmaf(s1, WVP0[c*3+1], s2*WVP0[c*3+2]));
}

// ---------------- KNN stage 1 (3-D), one wave per row, value-threshold 2-pass ----------------
__global__ __launch_bounds__(256) void knn1_kernel(const float* __restrict__ src,
                                                   int* __restrict__ idxout)
{
    int lane = threadIdx.x & 63, wave = threadIdx.x >> 6;
    int b7 = blockIdx.x & 7, sub = blockIdx.x >> 3;
    int batch = b7 >> 1;
    int rib = (sub*2 + (b7 & 1))*4 + wave;
    int row = batch*NN + rib;
    const float* sb = src + batch*NN*3;
    float xi0 = sb[rib*3], xi1 = sb[rib*3+1], xi2 = sb[rib*3+2];

    DECL16V
    for (int it = 0; it < 64; ++it) {
        int j = it*64 + lane;
        float dx = xi0 - sb[j*3], dy = xi1 - sb[j*3+1], dz = xi2 - sb[j*3+2];
        float d2 = fmaf(dx, dx, fmaf(dy, dy, dz*dz));
        if (d2 < v15) INSERT16V(d2);
    }
    float T = INFINITY;
    for (int t = 0; t < 16; ++t) {
        float g = v0;
#pragma unroll
        for (int off = 1; off < 64; off <<= 1) g = fminf(g, __shfl_xor(g, off, 64));
        unsigned long long b = __ballot(v0 == g);
        int f = __ffsll((long long)b) - 1;
        POP16V(lane == f);
        T = g;
    }
    unsigned long long below_mask = (lane == 63) ? 0x7fffffffffffffffull : ((1ull << lane) - 1ull);
    int base = 0;
    for (int it = 0; it < 64; ++it) {
        int j = it*64 + lane;
        float dx = xi0 - sb[j*3], dy = xi1 - sb[j*3+1], dz = xi2 - sb[j*3+2];
        float d2 = fmaf(dx, dx, fmaf(dy, dy, dz*dz));
        unsigned long long blt = __ballot(d2 < T);
        if (d2 < T) idxout[row*16 + base + __popcll(blt & below_mask)] = j;
        base += __popcll(blt);
    }
    for (int it = 0; it < 64 && base < 16; ++it) {
        int j = it*64 + lane;
        float dx = xi0 - sb[j*3], dy = xi1 - sb[j*3+1], dz = xi2 - sb[j*3+2];
        float d2 = fmaf(dx, dx, fmaf(dy, dy, dz*dz));
        unsigned long long beq = __ballot(d2 == T);
        int bel = __popcll(beq & below_mask);
        if (d2 == T && base + bel < 16) idxout[row*16 + base + bel] = j;
        base += __popcll(beq);
    }
}

// ---------------- split-bf16 MFMA GEMM: Y = X @ W^T (- S), X/W pre-split hi/lo ----------------
__global__ __launch_bounds__(256, 2) void gemm128(
    const ushort* __restrict__ XHg, const ushort* __restrict__ XLg,
    const ushort* __restrict__ WHb, const ushort* __restrict__ WLb,
    const float* __restrict__ S1, const float* __restrict__ S2,
    float* __restrict__ Ybase)
{
    __shared__ __align__(16) ushort WHs[128*128];   // 32 KB [c][d ^ ((c&7)<<3)]
    __shared__ __align__(16) ushort WLs[128*128];   // 32 KB
    int tid = threadIdx.x, lane = tid & 63, wave = tid >> 6;
    int y = blockIdx.y;
    const ushort* WH = WHb + y*16384;
    const ushort* WL = WLb + y*16384;
    float* Y = Ybase + (size_t)y*2097152;
    const float* S = (y == 1) ? S1 : ((y == 2) ? S2 : nullptr);
#pragma unroll
    for (int i = 0; i < 8; ++i) {
        int q = tid + 256*i;
        int c = q >> 4, d8 = q & 15;
        int widx = c*128 + ((d8*8) ^ ((c & 7) << 3));
        *(uint4*)&WHs[widx] = *(const uint4*)&WH[c*128 + d8*8];
        *(uint4*)&WLs[widx] = *(const uint4*)&WL[c*128 + d8*8];
    }
    int r = blockIdx.x*64 + wave*16 + (lane & 15);
    int dbase = (lane >> 4) * 8;
    bf16x8 AH[4], AL[4];
#pragma unroll
    for (int ks = 0; ks < 4; ++ks) {
        AH[ks] = *(const bf16x8*)&XHg[(size_t)r*128 + ks*32 + dbase];
        AL[ks] = *(const bf16x8*)&XLg[(size_t)r*128 + ks*32 + dbase];
    }
    __syncthreads();
    int rbase = blockIdx.x*64 + wave*16 + (lane >> 4)*4;
#pragma unroll
    for (int cb = 0; cb < 8; ++cb) {
        int cB = cb*16 + (lane & 15);
        f32x4 acc = {0.f, 0.f, 0.f, 0.f};
#pragma unroll
        for (int ks = 0; ks < 4; ++ks) {
            int bidx = cB*128 + ((ks*32 + dbase) ^ ((cB & 7) << 3));
            bf16x8 bh = *(const bf16x8*)&WHs[bidx];
            bf16x8 bl = *(const bf16x8*)&WLs[bidx];
            acc = __builtin_amdgcn_mfma_f32_16x16x32_bf16(AH[ks], bh, acc, 0, 0, 0);
            acc = __builtin_amdgcn_mfma_f32_16x16x32_bf16(AL[ks], bh, acc, 0, 0, 0);
            acc = __builtin_amdgcn_mfma_f32_16x16x32_bf16(AH[ks], bl, acc, 0, 0, 0);
        }
#pragma unroll
        for (int r2 = 0; r2 < 4; ++r2) {            // C/D: col=lane&15, row=(lane>>4)*4+reg
            int rA = rbase + r2;
            float o = acc[r2];
            if (S) o -= S[(size_t)rA*128 + cB];
            Y[(size_t)rA*128 + cB] = o;
        }
    }
}

// ---------------- gather attention: 4 rows/wave, 16 lanes x 8 dims per row ----------------
__global__ __launch_bounds__(512) void attn_kernel(
    const float* __restrict__ Q,  const float* __restrict__ GK, const float* __restrict__ GV,
    const float* __restrict__ BASE, const float* __restrict__ bv,
    const int* __restrict__ idx, float* __restrict__ outp, float* __restrict__ x2out,
    ushort* __restrict__ xh, ushort* __restrict__ xl)
{
    int tid = threadIdx.x;
    int lane = tid & 63, wave = tid >> 6;
    int xcd = blockIdx.x & 7, sub = blockIdx.x >> 3;     // grid 512; XCD pair owns a batch
    int batch = xcd >> 1;
    int band = sub*2 + (xcd & 1);                        // 0..127
    int rgrp = lane >> 4;
    int dimg = lane & 15;
    int rib = band*32 + wave*4 + rgrp;
    int row = batch*NN + rib;
    int d0 = dimg*8;
    int gbase = lane & 48;
    const float* GKb = GK + (size_t)batch*NN*NC;
    const float* GVb = GV + (size_t)batch*NN*NC;

    float4 q0 = *(const float4*)&Q[(size_t)row*NC + d0];
    float4 q1 = *(const float4*)&Q[(size_t)row*NC + d0 + 4];
    int jv = idx[row*16 + dimg];

    float sc[16];
#pragma unroll
    for (int k = 0; k < 16; ++k) {
        int j = __shfl(jv, gbase + k, 64);
        const float* gk = &GKb[(size_t)j*NC + d0];
        float4 g0 = *(const float4*)gk;
        float4 g1 = *(const float4*)(gk + 4);
        float p = fmaf(q0.x, g0.x, fmaf(q0.y, g0.y, fmaf(q0.z, g0.z, fmaf(q0.w, g0.w,
                  fmaf(q1.x, g1.x, fmaf(q1.y, g1.y, fmaf(q1.z, g1.z, q1.w*g1.w)))))));
#pragma unroll
        for (int off = 1; off < 16; off <<= 1) p += __shfl_xor(p, off, 64);
        sc[k] = p * SCALE_F;
    }
    float m = sc[0];
#pragma unroll
    for (int k = 1; k < 16; ++k) m = fmaxf(m, sc[k]);
    float wsum = 0.f, w[16];
#pragma unroll
    for (int k = 0; k < 16; ++k) { w[k] = expf(sc[k] - m); wsum += w[k]; }
    float inv = 1.f / wsum;

    float4 a0 = {0.f,0.f,0.f,0.f}, a1 = {0.f,0.f,0.f,0.f};
#pragma unroll
    for (int k = 0; k < 16; ++k) {
        int j = __shfl(jv, gbase + k, 64);
        const float* gv = &GVb[(size_t)j*NC + d0];
        float4 v0 = *(const float4*)gv;
        float4 v1 = *(const float4*)(gv + 4);
        float a = w[k] * inv;
        a0.x = fmaf(a, v0.x, a0.x); a0.y = fmaf(a, v0.y, a0.y);
        a0.z = fmaf(a, v0.z, a0.z); a0.w = fmaf(a, v0.w, a0.w);
        a1.x = fmaf(a, v1.x, a1.x); a1.y = fmaf(a, v1.y, a1.y);
        a1.z = fmaf(a, v1.z, a1.z); a1.w = fmaf(a, v1.w, a1.w);
    }
    float4 b0 = *(const float4*)&BASE[(size_t)row*NC + d0];
    float4 b1 = *(const float4*)&BASE[(size_t)row*NC + d0 + 4];
    float4 c0 = *(const float4*)&bv[d0];
    float4 c1 = *(const float4*)&bv[d0 + 4];
    a0.x += b0.x + c0.x; a0.y += b0.y + c0.y; a0.z += b0.z + c0.z; a0.w += b0.w + c0.w;
    a1.x += b1.x + c1.x; a1.y += b1.y + c1.y; a1.z += b1.z + c1.z; a1.w += b1.w + c1.w;
    *(float4*)&outp[(size_t)row*NC + d0]     = a0;
    *(float4*)&outp[(size_t)row*NC + d0 + 4] = a1;

    if (x2out != nullptr) {
        float x2 = fmaf(a0.x, a0.x, fmaf(a0.y, a0.y, fmaf(a0.z, a0.z, fmaf(a0.w, a0.w,
                   fmaf(a1.x, a1.x, fmaf(a1.y, a1.y, fmaf(a1.z, a1.z, a1.w*a1.w)))))));
#pragma unroll
        for (int off = 1; off < 16; off <<= 1) x2 += __shfl_xor(x2, off, 64);
        if (dimg == 0) x2out[row] = x2;
    }
    if (xh != nullptr) {
        ushort h0 = f2bf(a0.x), h1 = f2bf(a0.y), h2 = f2bf(a0.z), h3 = f2bf(a0.w);
        ushort h4 = f2bf(a1.x), h5 = f2bf(a1.y), h6 = f2bf(a1.z), h7 = f2bf(a1.w);
        uint4 ph;
        ph.x = (unsigned)h0 | ((unsigned)h1 << 16);
        ph.y = (unsigned)h2 | ((unsigned)h3 << 16);
        ph.z = (unsigned)h4 | ((unsigned)h5 << 16);
        ph.w = (unsigned)h6 | ((unsigned)h7 << 16);
        *(uint4*)&xh[(size_t)row*NC + d0] = ph;
        ushort l0 = f2bf(a0.x - bf2f(h0)), l1 = f2bf(a0.y - bf2f(h1));
        ushort l2 = f2bf(a0.z - bf2f(h2)), l3 = f2bf(a0.w - bf2f(h3));
        ushort l4 = f2bf(a1.x - bf2f(h4)), l5 = f2bf(a1.y - bf2f(h5));
        ushort l6 = f2bf(a1.z - bf2f(h6)), l7 = f2bf(a1.w - bf2f(h7));
        uint4 pl;
        pl.x = (unsigned)l0 | ((unsigned)l1 << 16);
        pl.y = (unsigned)l2 | ((unsigned)l3 << 16);
        pl.z = (unsigned)l4 | ((unsigned)l5 << 16);
        pl.w = (unsigned)l6 | ((unsigned)l7 << 16);
        *(uint4*)&xl[(size_t)row*NC + d0] = pl;
    }
}

// ---------------- KNN stage 2: 3-term split-bf16 MFMA Gram, half-sweep blocks ----------------
// Grid 1024: 128 bands x 2 column-halves x 4 batches. 32 rows/block, 64-col tiles, 32 phases.
// LDS 49 KB -> 3 blocks/CU. VGPR discipline (R9-R11 lessons): keys(32)+AH(16) stay in regs;
// AL row-band fragments are RE-LOADED from global each phase (same 4 addrs -> L1/L2 hit) with
// an asm opacity to stop loop-invariant hoisting. Live set ~58 <= 64 -> 8 waves/SIMD allowed.
// NEVER force launch_bounds min-waves above 2: caps VGPR below live set -> scratch spill.
#define SCAN_STEP(CP, X2S, REFRESH) do { \
    float4 dd = *(const float4*)&DT[dtrd]; \
    float4 xx = *(const float4*)&(X2S)[slotl*4]; \
    float d2q0 = fmaf(-2.f, dd.x, xx.x); \
    float d2q1 = fmaf(-2.f, dd.y, xx.y); \
    float d2q2 = fmaf(-2.f, dd.z, xx.z); \
    float d2q3 = fmaf(-2.f, dd.w, xx.w); \
    bool p0 = d2q0 <= Trow, p1 = d2q1 <= Trow, p2 = d2q2 <= Trow, p3 = d2q3 <= Trow; \
    if (__ballot(p0 | p1 | p2 | p3)) { \
        unsigned g0 = (unsigned)(__ballot(p0) >> grpsh) & 0xFFFFu; \
        unsigned g1 = (unsigned)(__ballot(p1) >> grpsh) & 0xFFFFu; \
        unsigned g2 = (unsigned)(__ballot(p2) >> grpsh) & 0xFFFFu; \
        unsigned g3 = (unsigned)(__ballot(p3) >> grpsh) & 0xFFFFu; \
        int c0n = __popc(g0), c1n = __popc(g1), c2n = __popc(g2), c3n = __popc(g3); \
        int total = c0n + c1n + c2n + c3n; \
        if (total <= 32) { \
            if (p0) BUF[srow][__popc(g0 & lowm)]             = mkkey(d2q0, (CP) + slotl*4 + 0); \
            if (p1) BUF[srow][c0n + __popc(g1 & lowm)]       = mkkey(d2q1, (CP) + slotl*4 + 1); \
            if (p2) BUF[srow][c0n + c1n + __popc(g2 & lowm)] = mkkey(d2q2, (CP) + slotl*4 + 2); \
            if (p3) BUF[srow][c0n + c1n + c2n + __popc(g3 & lowm)] = mkkey(d2q3, (CP) + slotl*4 + 3); \
            if (slotl < total) { \
                unsigned long long k = BUF[srow][slotl]; \
                if (k < K15) INSERT16K(k); \
            } \
            if (16 + slotl < total) { \
                unsigned long long k = BUF[srow][16 + slotl]; \
                if (k < K15) INSERT16K(k); \
            } \
        } else { \
            unsigned long long kq; \
            if (p0) { kq = mkkey(d2q0, (CP) + slotl*4 + 0); if (kq < K15) INSERT16K(kq); } \
            if (p1) { kq = mkkey(d2q1, (CP) + slotl*4 + 1); if (kq < K15) INSERT16K(kq); } \
            if (p2) { kq = mkkey(d2q2, (CP) + slotl*4 + 2); if (kq < K15) INSERT16K(kq); } \
            if (p3) { kq = mkkey(d2q3, (CP) + slotl*4 + 3); if (kq < K15) INSERT16K(kq); } \
        } \
    } \
    if (REFRESH) { \
        unsigned long long tk = K15; \
        _Pragma("unroll") \
        for (int off = 1; off < 16; off <<= 1) { \
            unsigned long long o = __shfl_xor(tk, off, 64); \
            tk = (o < tk) ? o : tk; \
        } \
        unsigned uu = (unsigned)(tk >> 32); \
        uu = (uu > 0xFF800000u) ? 0xFF800000u : uu; \
        uu = (uu & 0x80000000u) ? (uu ^ 0x80000000u) : ~uu; \
        Trow = __uint_as_float(uu); \
    } \
} while (0)

__global__ __launch_bounds__(512, 2) void knn2_kernel(const ushort* __restrict__ XHg,
                                                      const ushort* __restrict__ XLg,
                                                      const float* __restrict__ x2g,
                                                      unsigned long long* __restrict__ kpart)
{
    __shared__ __align__(16) ushort XCH[64*128];        // 16 KB [c][d ^ ((c&7)<<3)]
    __shared__ __align__(16) ushort XCL[64*128];        // 16 KB
    __shared__ __align__(16) float  DT[32*64];          //  8 KB rotation swizzle
    __shared__ unsigned long long   BUF[32][33];        //  8.25 KB survivor buffers (cap 32)
    __shared__ __align__(16) float  X2T[2][64];         //  0.5 KB
    int tid = threadIdx.x;
    int lane = tid & 63, wave = tid >> 6;
    int b = blockIdx.x;                                 // grid 1024
    int xcd = b & 7, half = (b >> 3) & 1, sub = b >> 4; // XCD pair owns a batch
    int batch = xcd >> 1;
    int band = sub*2 + (xcd & 1);                       // 0..127
    const ushort* XHb = XHg + (size_t)batch*NN*NC;
    const ushort* XLb = XLg + (size_t)batch*NN*NC;
    const float*  x2b = x2g + (size_t)batch*NN;
    int r0 = band*32;
    int cbase = half*2048;

    int rowblk = wave & 1, colblk = wave >> 1;
    int dbase = (lane >> 4) * 8;
    int gr = r0 + rowblk*16 + (lane & 15);
    bf16x8 AH[4];
#pragma unroll
    for (int ks = 0; ks < 4; ++ks) {
        AH[ks] = *(const bf16x8*)&XHb[(size_t)gr*NC + ks*32 + dbase];
    }
    const ushort* ALp0 = XLb + (size_t)gr*NC + dbase;   // per-lane AL base (row-band lo)
    int cB = colblk*16 + (lane & 15);

    int srow = tid >> 4, slotl = tid & 15;
    int grpsh = lane & 48;
    unsigned lowm = (1u << slotl) - 1u;
    int dtrd = srow*64 + ((slotl*4 + 4*srow) & 63);
    float Trow = INFINITY;
    DECL16K

    for (int t = 0; t < 32; ++t) {
        int c0 = cbase + t*64;
        __syncthreads();                                // MFMA(t-1) done: DT ready, XC free
        // stage hi+lo col tiles with XOR swizzle (each global byte read exactly once)
#pragma unroll
        for (int i = 0; i < 2; ++i) {
            int qq = tid + 512*i;
            int c = qq >> 4, d8 = qq & 15;
            int widx = c*128 + ((d8*8) ^ ((c & 7) << 3));
            *(uint4*)&XCH[widx] = *(const uint4*)&XHb[(size_t)(c0 + c)*NC + d8*8];
            *(uint4*)&XCL[widx] = *(const uint4*)&XLb[(size_t)(c0 + c)*NC + d8*8];
        }
        // AL row-band fragments: re-load per phase (L1/L2-resident), opaque to stop hoisting
        unsigned long palu = (unsigned long)ALp0;
        asm volatile("" : "+v"(palu));
        const ushort* ALp = (const ushort*)palu;
        bf16x8 al0 = *(const bf16x8*)(ALp + 0*32);
        bf16x8 al1 = *(const bf16x8*)(ALp + 1*32);
        bf16x8 al2 = *(const bf16x8*)(ALp + 2*32);
        bf16x8 al3 = *(const bf16x8*)(ALp + 3*32);
        if (tid < 64) X2T[t & 1][tid] = x2b[c0 + tid];
        if (t > 0) {
            const float* x2s = X2T[(t - 1) & 1];
            SCAN_STEP(c0 - 64, x2s, 1);
        }
        __syncthreads();                                // staging visible; DT free
        // MFMA: one 16x16 tile per wave, 3-term split-bf16 (hh + lh + hl), K=128
        f32x4 acc = {0.f, 0.f, 0.f, 0.f};
#pragma unroll
        for (int ks = 0; ks < 4; ++ks) {
            int bidx = cB*128 + ((ks*32 + dbase) ^ ((cB & 7) << 3));
            bf16x8 bh = *(const bf16x8*)&XCH[bidx];
            bf16x8 bl = *(const bf16x8*)&XCL[bidx];
            bf16x8 alk = (ks == 0) ? al0 : ((ks == 1) ? al1 : ((ks == 2) ? al2 : al3));
            acc = __builtin_amdgcn_mfma_f32_16x16x32_bf16(AH[ks], bh, acc, 0, 0, 0);
            acc = __builtin_amdgcn_mfma_f32_16x16x32_bf16(alk,    bh, acc, 0, 0, 0);
            acc = __builtin_amdgcn_mfma_f32_16x16x32_bf16(AH[ks], bl, acc, 0, 0, 0);
        }
#pragma unroll
        for (int r2 = 0; r2 < 4; ++r2) {                // C/D: col=lane&15, row=(lane>>4)*4+reg
            int rA = rowblk*16 + (lane >> 4)*4 + r2;
            DT[rA*64 + (((cB & ~3) + 4*rA) & 63) + (cB & 3)] = acc[r2];
        }
    }
    __syncthreads();
    {   // scan last tile (t=31's DT), parity 31&1 = 1
        const float* x2s = X2T[1];
        SCAN_STEP(cbase + 31*64, x2s, 0);
    }
    // per-row 16-lane pop-merge; emit this half's sorted top-16 keys
    int grow = batch*NN + r0 + srow;
    for (int tt = 0; tt < 16; ++tt) {
        unsigned long long g = K0;
#pragma unroll
        for (int off = 1; off < 16; off <<= 1) {
            unsigned long long o = __shfl_xor(g, off, 64);
            g = (o < g) ? o : g;
        }
        if (slotl == 0) kpart[(size_t)grow*32 + half*16 + tt] = g;
        POP16K(K0 == g);
    }
}

// merge two sorted 16-key half-lists per row -> final indices (exact lex order)
__global__ __launch_bounds__(256) void knn2_merge(const unsigned long long* __restrict__ KP,
                                                  int* __restrict__ idxout)
{
    int row = blockIdx.x*256 + threadIdx.x;      // grid 64
    const unsigned long long* a = &KP[(size_t)row*32];
    const unsigned long long* bq = a + 16;
    int ia = 0, ib = 0;
#pragma unroll
    for (int t = 0; t < 16; ++t) {
        unsigned long long ka = a[ia], kb = bq[ib];
        bool ta = ka < kb;
        idxout[row*16 + t] = (int)(unsigned)((ta ? ka : kb) & 0xFFFFFFFFull);
        ia += ta ? 1 : 0; ib += ta ? 0 : 1;
    }
}

// ---------------- final fused LN / linear / LN / transpose ----------------
__global__ __launch_bounds__(256) void final_kernel(
    const float* __restrict__ tgt, const float* __restrict__ att,
    const float* __restrict__ Wl, const float* __restrict__ bl,
    const float* __restrict__ g0, const float* __restrict__ b0,
    const float* __restrict__ g1, const float* __restrict__ b1,
    float* __restrict__ outp)
{
    __shared__ float WL[128*128];
    int tid = threadIdx.x;
    for (int f = tid; f < 16384; f += 256) {
        int c = f >> 7, d = f & 127;
        WL[d*128 + (c ^ (d & 14))] = Wl[f];
    }
    __syncthreads();
    int lane = tid & 63, wave = tid >> 6;
    float2 gg0 = *(const float2*)&g0[2*lane];
    float2 bb0 = *(const float2*)&b0[2*lane];
    float2 gg1 = *(const float2*)&g1[2*lane];
    float2 bb1 = *(const float2*)&b1[2*lane];
    float2 bl2 = *(const float2*)&bl[2*lane];
    for (int it = 0; it < 4; ++it) {
        int row0 = blockIdx.x*64 + it*16 + wave*4;
        float2 tg[4];
        float lnx[4], lny[4];
#pragma unroll
        for (int r = 0; r < 4; ++r) {
            int row = row0 + r;
            tg[r] = *(const float2*)&tgt[row*128 + 2*lane];
            float2 at = *(const float2*)&att[row*128 + 2*lane];
            float ox = tg[r].x + at.x, oy = tg[r].y + at.y;
            float s = ox + oy;
#pragma unroll
            for (int off = 1; off < 64; off <<= 1) s += __shfl_xor(s, off, 64);
            float mu = s * (1.f/128.f);
            float dx = ox - mu, dy = oy - mu;
            float vv = fmaf(dx, dx, dy*dy);
#pragma unroll
            for (int off = 1; off < 64; off <<= 1) vv += __shfl_xor(vv, off, 64);
            float rstd = rsqrtf(vv * (1.f/128.f) + 1e-5f);
            lnx[r] = dx * rstd * gg0.x + bb0.x;
            lny[r] = dy * rstd * gg0.y + bb0.y;
        }
        float2 acc[4];
#pragma unroll
        for (int r = 0; r < 4; ++r) { acc[r].x = 0.f; acc[r].y = 0.f; }
#pragma unroll 8
        for (int dh = 0; dh < 64; ++dh) {
            int cidx = (2*lane) ^ ((2*dh) & 14);
            float2 wa = *(const float2*)&WL[(2*dh)*128 + cidx];
            float2 wb = *(const float2*)&WL[(2*dh+1)*128 + cidx];
#pragma unroll
            for (int r = 0; r < 4; ++r) {
                float xa = rl_f(lnx[r], dh);
                float xb = rl_f(lny[r], dh);
                acc[r].x = fmaf(xa, wa.x, acc[r].x);
                acc[r].y = fmaf(xa, wa.y, acc[r].y);
                acc[r].x = fmaf(xb, wb.x, acc[r].x);
                acc[r].y = fmaf(xb, wb.y, acc[r].y);
            }
        }
#pragma unroll
        for (int r = 0; r < 4; ++r) {
            int row = row0 + r;
            float zx = tg[r].x + acc[r].x + bl2.x;
            float zy = tg[r].y + acc[r].y + bl2.y;
            float s = zx + zy;
#pragma unroll
            for (int off = 1; off < 64; off <<= 1) s += __shfl_xor(s, off, 64);
            float mu = s * (1.f/128.f);
            float dx = zx - mu, dy = zy - mu;
            float vv = fmaf(dx, dx, dy*dy);
#pragma unroll
            for (int off = 1; off < 64; off <<= 1) vv += __shfl_xor(vv, off, 64);
            float rstd = rsqrtf(vv * (1.f/128.f) + 1e-5f);
            float2 res;
            res.x = dx * rstd * gg1.x + bb1.x;
            res.y = dy * rstd * gg1.y + bb1.y;
            int b = row >> 12, n = row & 4095;
            *(float2*)&outp[((size_t)n*NB + b)*128 + 2*lane] = res;
        }
    }
}

extern "C" void kernel_launch(void* const* d_in, const int* in_sizes, int n_in,
                              void* d_out, int out_size, void* d_ws, size_t ws_size,
                              hipStream_t stream)
{
    (void)in_sizes; (void)n_in; (void)out_size; (void)ws_size;
    const float* src = (const float*)d_in[0];
    const float* tgt = (const float*)d_in[1];
    const float* Wq0 = (const float*)d_in[2];
    const float* Wk0 = (const float*)d_in[3];
    const float* Wv0 = (const float*)d_in[4];
    const float* Wq1 = (const float*)d_in[5];
    const float* Wk1 = (const float*)d_in[6];
    const float* Wv1 = (const float*)d_in[7];
    const float* Wp0 = (const float*)d_in[8];
    const float* bp0 = (const float*)d_in[9];
    const float* Wp1 = (const float*)d_in[10];
    const float* bp1 = (const float*)d_in[11];
    const float* Wl  = (const float*)d_in[12];
    const float* bl  = (const float*)d_in[13];
    const float* g0  = (const float*)d_in[14];
    const float* b0  = (const float*)d_in[15];
    const float* g1  = (const float*)d_in[16];
    const float* b1  = (const float*)d_in[17];
    float* out = (float*)d_out;

    float* A0   = (float*)d_ws;                  // Ybase: A0..A4 contiguous
    float* A1   = A0 + 2097152;
    float* A2   = A1 + 2097152;
    float* A3   = A2 + 2097152;
    float* A4   = A3 + 2097152;
    float* OUT1 = A4 + 2097152;
    int*   IDX1 = (int*)(OUT1 + 2097152);
    int*   IDX2 = IDX1 + NROWS*16;
    float* X2G  = (float*)(IDX2 + NROWS*16);
    float* WKP0 = X2G + NROWS;
    float* BK0  = WKP0 + 384;
    float* WVP0 = BK0 + 128;
    float* BV0  = WVP0 + 384;
    float* WKD  = BV0 + 128;
    float* MV1  = WKD + 16384;
    float* WVD  = MV1 + 16384;
    float* BV1  = WVD + 16384;
    ushort* WSH = (ushort*)(BV1 + 128);          // 7 x 16384 bf16-hi weight slots
    ushort* WSL = WSH + 7*16384;                 // 7 x 16384 bf16-lo
    ushort* XH  = WSL + 7*16384;                 // 4 MB (tgt-split, then OUT1-split)
    ushort* XL  = XH + (size_t)NROWS*NC;         // 4 MB
    unsigned long long* KPART = (unsigned long long*)A0;  // 4 MB scratch, dead at knn2 time

    combo_small<<<dim3(2), dim3(512), 0, stream>>>(Wk0, Wv0, Wp0, bp0, WKP0, BK0, WVP0, BV0);
    combo_big<<<dim3(129), dim3(256), 0, stream>>>(Wk1, Wv1, Wp1, bp1, WKD, MV1, WVD, BV1);
    // weight slots: 0=Wq0 1=Wk0 2=Wv0 | 3=Wq1 4=WKD 5=WVD 6=MV1
    split7<<<dim3(64, 7), dim3(256), 0, stream>>>(Wq0, Wk0, Wv0, Wq1, WKD, WVD, MV1, WSH, WSL);
    srcproj<<<dim3(8192), dim3(256), 0, stream>>>(src, WKP0, WVP0, A3, A4);
    splitx<<<dim3(1024), dim3(256), 0, stream>>>(tgt, XH, XL);      // XH/XL = tgt split
    knn1_kernel<<<dim3(4096), dim3(256), 0, stream>>>(src, IDX1);
    // stage-1 GEMMs: A0 = tgt@Wq0^T ; A1 = tgt@Wk0^T - srcKp(A3) ; A2 = tgt@Wv0^T - srcVp(A4)
    gemm128<<<dim3(256, 3), dim3(256), 0, stream>>>(XH, XL, WSH, WSL, A3, A4, A0);
    attn_kernel<<<dim3(512), dim3(512), 0, stream>>>(A0, A1, A2, A4, BV0, IDX1, OUT1, X2G, XH, XL);
    knn2_kernel<<<dim3(1024), dim3(512), 0, stream>>>(XH, XL, X2G, KPART);
    knn2_merge<<<dim3(64), dim3(256), 0, stream>>>(KPART, IDX2);
    // stage-2 GEMMs: A0 = Q1 ; A1 = GK2 ; A2 = GV2 ; A3 = BASE2 (X@MV1^T)
    gemm128<<<dim3(256, 4), dim3(256), 0, stream>>>(XH, XL, WSH + 3*16384, WSL + 3*16384,
                                                    nullptr, nullptr, A0);
    attn_kernel<<<dim3(512), dim3(512), 0, stream>>>(A0, A1, A2, A3, BV1, IDX2, OUT1, nullptr, nullptr, nullptr);
    final_kernel<<<dim3(256), dim3(256), 0, stream>>>(tgt, OUT1, Wl, bl, g0, b0, g1, b1, out);
}

// Round 13
// 550.640 us; speedup vs baseline: 1.1308x; 1.1308x over previous
//
#include <hip/hip_runtime.h>
#include <math.h>

#define NB 4
#define NN 4096
#define NC 128
#define NROWS (NB*NN)
#define SCALE_F 0.08838834764831845f   // 1/sqrt(128)

using bf16x8 = __attribute__((ext_vector_type(8))) short;
using f32x4  = __attribute__((ext_vector_type(4))) float;

__device__ __forceinline__ float rl_f(float x, int l) {
    return __int_as_float(__builtin_amdgcn_readlane(__float_as_int(x), l));
}
__device__ __forceinline__ ushort f2bf(float x) {          // fp32 -> bf16 RNE
    unsigned u = __float_as_uint(x);
    return (ushort)((u + 0x7FFF + ((u >> 16) & 1)) >> 16);
}
__device__ __forceinline__ float bf2f(ushort b) { return __uint_as_float(((unsigned)b) << 16); }

// monotone key: (order-preserving float bits) << 32 | index  — lex (value, idx) asc
__device__ __forceinline__ unsigned long long mkkey(float d2, int idx) {
    unsigned u = __float_as_uint(d2);
    u ^= ((unsigned)((int)u >> 31)) | 0x80000000u;
    return ((unsigned long long)u << 32) | (unsigned)idx;
}

// ---- 16-deep sorted (ascending) float register lists (knn1) ----
#define DECL16V \
    float v0=INFINITY,v1=INFINITY,v2=INFINITY,v3=INFINITY,v4=INFINITY,v5=INFINITY,v6=INFINITY,v7=INFINITY, \
          v8=INFINITY,v9=INFINITY,v10=INFINITY,v11=INFINITY,v12=INFINITY,v13=INFINITY,v14=INFINITY,v15=INFINITY;

#define INSERT16V(dv) do { float d_=(dv); \
    bool m0=d_<v0,m1=d_<v1,m2=d_<v2,m3=d_<v3,m4=d_<v4,m5=d_<v5,m6=d_<v6,m7=d_<v7, \
         m8=d_<v8,m9=d_<v9,m10=d_<v10,m11=d_<v11,m12=d_<v12,m13=d_<v13,m14=d_<v14,m15=d_<v15; \
    v15=m14?v14:(m15?d_:v15); v14=m13?v13:(m14?d_:v14); v13=m12?v12:(m13?d_:v13); v12=m11?v11:(m12?d_:v12); \
    v11=m10?v10:(m11?d_:v11); v10=m9?v9:(m10?d_:v10); v9 =m8?v8:(m9?d_:v9);  v8 =m7?v7:(m8?d_:v8); \
    v7 =m6?v6:(m7?d_:v7);   v6 =m5?v5:(m6?d_:v6);   v5 =m4?v4:(m5?d_:v5);  v4 =m3?v3:(m4?d_:v4); \
    v3 =m2?v2:(m3?d_:v3);   v2 =m1?v1:(m2?d_:v2);   v1 =m0?v0:(m1?d_:v1);  v0 =m0?d_:v0; } while(0)

#define POP16V(p) do { bool p_=(p); \
    v0=p_?v1:v0; v1=p_?v2:v1; v2=p_?v3:v2; v3=p_?v4:v3; v4=p_?v5:v4; v5=p_?v6:v5; v6=p_?v7:v6; v7=p_?v8:v7; \
    v8=p_?v9:v8; v9=p_?v10:v9; v10=p_?v11:v10; v11=p_?v12:v11; v12=p_?v13:v12; v13=p_?v14:v13; v14=p_?v15:v14; \
    v15=p_?INFINITY:v15; } while(0)

// ---- 16-deep sorted (ascending) u64-key register lists (knn2) ----
#define KMAX16 0xFFFFFFFFFFFFFFFFull
#define DECL16K \
    unsigned long long K0=KMAX16,K1=KMAX16,K2=KMAX16,K3=KMAX16,K4=KMAX16,K5=KMAX16,K6=KMAX16,K7=KMAX16, \
                       K8=KMAX16,K9=KMAX16,K10=KMAX16,K11=KMAX16,K12=KMAX16,K13=KMAX16,K14=KMAX16,K15=KMAX16;

#define INSERT16K(kv) do { unsigned long long k_=(kv); \
    bool m0=k_<K0,m1=k_<K1,m2=k_<K2,m3=k_<K3,m4=k_<K4,m5=k_<K5,m6=k_<K6,m7=k_<K7, \
         m8=k_<K8,m9=k_<K9,m10=k_<K10,m11=k_<K11,m12=k_<K12,m13=k_<K13,m14=k_<K14,m15=k_<K15; \
    K15=m14?K14:(m15?k_:K15); K14=m13?K13:(m14?k_:K14); K13=m12?K12:(m13?k_:K13); K12=m11?K11:(m12?k_:K12); \
    K11=m10?K10:(m11?k_:K11); K10=m9?K9:(m10?k_:K10);   K9 =m8?K8:(m9?k_:K9);    K8 =m7?K7:(m8?k_:K8); \
    K7 =m6?K6:(m7?k_:K7);     K6 =m5?K5:(m6?k_:K6);     K5 =m4?K4:(m5?k_:K5);    K4 =m3?K3:(m4?k_:K4); \
    K3 =m2?K2:(m3?k_:K3);     K2 =m1?K1:(m2?k_:K2);     K1 =m0?K0:(m1?k_:K1);    K0 =m0?k_:K0; } while(0)

#define POP16K(p) do { bool p_=(p); \
    K0=p_?K1:K0; K1=p_?K2:K1; K2=p_?K3:K2; K3=p_?K4:K3; K4=p_?K5:K4; K5=p_?K6:K5; K6=p_?K7:K6; K7=p_?K8:K7; \
    K8=p_?K9:K8; K9=p_?K10:K9; K10=p_?K11:K10; K11=p_?K12:K11; K12=p_?K13:K12; K13=p_?K14:K13; K14=p_?K15:K14; \
    K15=p_?KMAX16:K15; } while(0)

// ---------------- tiny weight combos ----------------
__global__ void combo_small(const float* __restrict__ Wk0, const float* __restrict__ Wv0,
                            const float* __restrict__ Wp0, const float* __restrict__ bp0,
                            float* __restrict__ WKP0, float* __restrict__ BK0,
                            float* __restrict__ WVP0, float* __restrict__ BV0)
{
    int task = blockIdx.x * 512 + threadIdx.x;
    if (task >= 1024) return;
    int mat = task >> 9; int rem = task & 511;
    int c = rem >> 2, t = rem & 3;
    const float* W = mat ? Wv0 : Wk0;
    float s = 0.f;
    if (t < 3) {
        for (int d = 0; d < 128; ++d) s = fmaf(W[c*128+d], Wp0[d*3+t], s);
        (mat ? WVP0 : WKP0)[c*3+t] = s;
    } else {
        for (int d = 0; d < 128; ++d) s = fmaf(W[c*128+d], bp0[d], s);
        (mat ? BV0 : BK0)[c] = s;
    }
}

// WKD = Wk1 - Wk1@Wp1 ; MV1 = Wv1@Wp1 ; WVD = Wv1 - MV1 ; BV1 = Wv1@bp1
__global__ void combo_big(const float* __restrict__ Wk1, const float* __restrict__ Wv1,
                          const float* __restrict__ Wp1, const float* __restrict__ bp1,
                          float* __restrict__ WKD, float* __restrict__ MV1,
                          float* __restrict__ WVD, float* __restrict__ BV1)
{
    int task = blockIdx.x * 256 + threadIdx.x;   // grid 129 x 256
    if (task >= 32896) return;
    if (task < 32768) {
        int mat = task >> 14; int rem = task & 16383;
        int c = rem >> 7, tcol = rem & 127;
        const float* W = mat ? Wv1 : Wk1;
        float s = 0.f;
        for (int d = 0; d < 128; ++d) s = fmaf(W[c*128+d], Wp1[d*128+tcol], s);
        if (mat) { MV1[rem] = s; WVD[rem] = Wv1[rem] - s; }
        else     { WKD[rem] = Wk1[rem] - s; }
    } else {
        int c = task - 32768;
        float s = 0.f;
        for (int d = 0; d < 128; ++d) s = fmaf(Wv1[c*128+d], bp1[d], s);
        BV1[c] = s;
    }
}

// split 7 weight matrices (16384 elems each) into contiguous bf16 hi/lo slots
__global__ void split7(const float* __restrict__ W0, const float* __restrict__ W1,
                       const float* __restrict__ W2, const float* __restrict__ W3,
                       const float* __restrict__ W4, const float* __restrict__ W5,
                       const float* __restrict__ W6,
                       ushort* __restrict__ WSH, ushort* __restrict__ WSL)
{
    int y = blockIdx.y;
    const float* W;
    switch (y) {
        case 0: W = W0; break; case 1: W = W1; break; case 2: W = W2; break;
        case 3: W = W3; break; case 4: W = W4; break; case 5: W = W5; break;
        default: W = W6; break;
    }
    int i = blockIdx.x*256 + threadIdx.x;          // grid.x = 64
    float v = W[i];
    ushort h = f2bf(v);
    WSH[y*16384 + i] = h;
    WSL[y*16384 + i] = f2bf(v - bf2f(h));
}

// split fp32 activation matrix into bf16 hi/lo (8 elems/thread)
__global__ void splitx(const float* __restrict__ X, ushort* __restrict__ XH,
                       ushort* __restrict__ XL)
{
    int i = (blockIdx.x*256 + threadIdx.x) * 8;    // grid 1024
    float4 a = *(const float4*)&X[i];
    float4 b = *(const float4*)&X[i+4];
    ushort h0=f2bf(a.x),h1=f2bf(a.y),h2=f2bf(a.z),h3=f2bf(a.w);
    ushort h4=f2bf(b.x),h5=f2bf(b.y),h6=f2bf(b.z),h7=f2bf(b.w);
    uint4 ph;
    ph.x=(unsigned)h0|((unsigned)h1<<16); ph.y=(unsigned)h2|((unsigned)h3<<16);
    ph.z=(unsigned)h4|((unsigned)h5<<16); ph.w=(unsigned)h6|((unsigned)h7<<16);
    *(uint4*)&XH[i] = ph;
    ushort l0=f2bf(a.x-bf2f(h0)),l1=f2bf(a.y-bf2f(h1)),l2=f2bf(a.z-bf2f(h2)),l3=f2bf(a.w-bf2f(h3));
    ushort l4=f2bf(b.x-bf2f(h4)),l5=f2bf(b.y-bf2f(h5)),l6=f2bf(b.z-bf2f(h6)),l7=f2bf(b.w-bf2f(h7));
    uint4 pl;
    pl.x=(unsigned)l0|((unsigned)l1<<16); pl.y=(unsigned)l2|((unsigned)l3<<16);
    pl.z=(unsigned)l4|((unsigned)l5<<16); pl.w=(unsigned)l6|((unsigned)l7<<16);
    *(uint4*)&XL[i] = pl;
}

__global__ void srcproj(const float* __restrict__ src, const float* __restrict__ WKP0,
                        const float* __restrict__ WVP0,
                        float* __restrict__ srcKp, float* __restrict__ srcVp)
{
    int gid = blockIdx.x * 256 + threadIdx.x;
    int i = gid >> 7, c = gid & 127;
    float s0 = src[i*3+0], s1 = src[i*3+1], s2 = src[i*3+2];
    srcKp[gid] = fmaf(s0, WKP0[c*3+0], fmaf(s1, WKP0[c*3+1], s2*WKP0[c*3+2]));
    srcVp[gid] = fmaf(s0, WVP0[c*3+0], fmaf(s1, WVP0[c*3+1], s2*WVP0[c*3+2]));
}

// ---------------- KNN stage 1 (3-D), one wave per row, value-threshold 2-pass ----------------
__global__ __launch_bounds__(256) void knn1_kernel(const float* __restrict__ src,
                                                   int* __restrict__ idxout)
{
    int lane = threadIdx.x & 63, wave = threadIdx.x >> 6;
    int b7 = blockIdx.x & 7, sub = blockIdx.x >> 3;
    int batch = b7 >> 1;
    int rib = (sub*2 + (b7 & 1))*4 + wave;
    int row = batch*NN + rib;
    const float* sb = src + batch*NN*3;
    float xi0 = sb[rib*3], xi1 = sb[rib*3+1], xi2 = sb[rib*3+2];

    DECL16V
    for (int it = 0; it < 64; ++it) {
        int j = it*64 + lane;
        float dx = xi0 - sb[j*3], dy = xi1 - sb[j*3+1], dz = xi2 - sb[j*3+2];
        float d2 = fmaf(dx, dx, fmaf(dy, dy, dz*dz));
        if (d2 < v15) INSERT16V(d2);
    }
    float T = INFINITY;
    for (int t = 0; t < 16; ++t) {
        float g = v0;
#pragma unroll
        for (int off = 1; off < 64; off <<= 1) g = fminf(g, __shfl_xor(g, off, 64));
        unsigned long long b = __ballot(v0 == g);
        int f = __ffsll((long long)b) - 1;
        POP16V(lane == f);
        T = g;
    }
    unsigned long long below_mask = (lane == 63) ? 0x7fffffffffffffffull : ((1ull << lane) - 1ull);
    int base = 0;
    for (int it = 0; it < 64; ++it) {
        int j = it*64 + lane;
        float dx = xi0 - sb[j*3], dy = xi1 - sb[j*3+1], dz = xi2 - sb[j*3+2];
        float d2 = fmaf(dx, dx, fmaf(dy, dy, dz*dz));
        unsigned long long blt = __ballot(d2 < T);
        if (d2 < T) idxout[row*16 + base + __popcll(blt & below_mask)] = j;
        base += __popcll(blt);
    }
    for (int it = 0; it < 64 && base < 16; ++it) {
        int j = it*64 + lane;
        float dx = xi0 - sb[j*3], dy = xi1 - sb[j*3+1], dz = xi2 - sb[j*3+2];
        float d2 = fmaf(dx, dx, fmaf(dy, dy, dz*dz));
        unsigned long long beq = __ballot(d2 == T);
        int bel = __popcll(beq & below_mask);
        if (d2 == T && base + bel < 16) idxout[row*16 + base + bel] = j;
        base += __popcll(beq);
    }
}

// ---------------- split-bf16 MFMA GEMM: Y = X @ W^T (- S), X/W pre-split hi/lo ----------------
__global__ __launch_bounds__(256, 2) void gemm128(
    const ushort* __restrict__ XHg, const ushort* __restrict__ XLg,
    const ushort* __restrict__ WHb, const ushort* __restrict__ WLb,
    const float* __restrict__ S1, const float* __restrict__ S2,
    float* __restrict__ Ybase)
{
    __shared__ __align__(16) ushort WHs[128*128];   // 32 KB [c][d ^ ((c&7)<<3)]
    __shared__ __align__(16) ushort WLs[128*128];   // 32 KB
    int tid = threadIdx.x, lane = tid & 63, wave = tid >> 6;
    int y = blockIdx.y;
    const ushort* WH = WHb + y*16384;
    const ushort* WL = WLb + y*16384;
    float* Y = Ybase + (size_t)y*2097152;
    const float* S = (y == 1) ? S1 : ((y == 2) ? S2 : nullptr);
#pragma unroll
    for (int i = 0; i < 8; ++i) {
        int q = tid + 256*i;
        int c = q >> 4, d8 = q & 15;
        int widx = c*128 + ((d8*8) ^ ((c & 7) << 3));
        *(uint4*)&WHs[widx] = *(const uint4*)&WH[c*128 + d8*8];
        *(uint4*)&WLs[widx] = *(const uint4*)&WL[c*128 + d8*8];
    }
    int r = blockIdx.x*64 + wave*16 + (lane & 15);
    int dbase = (lane >> 4) * 8;
    bf16x8 AH[4], AL[4];
#pragma unroll
    for (int ks = 0; ks < 4; ++ks) {
        AH[ks] = *(const bf16x8*)&XHg[(size_t)r*128 + ks*32 + dbase];
        AL[ks] = *(const bf16x8*)&XLg[(size_t)r*128 + ks*32 + dbase];
    }
    __syncthreads();
    int rbase = blockIdx.x*64 + wave*16 + (lane >> 4)*4;
#pragma unroll
    for (int cb = 0; cb < 8; ++cb) {
        int cB = cb*16 + (lane & 15);
        f32x4 acc = {0.f, 0.f, 0.f, 0.f};
#pragma unroll
        for (int ks = 0; ks < 4; ++ks) {
            int bidx = cB*128 + ((ks*32 + dbase) ^ ((cB & 7) << 3));
            bf16x8 bh = *(const bf16x8*)&WHs[bidx];
            bf16x8 bl = *(const bf16x8*)&WLs[bidx];
            acc = __builtin_amdgcn_mfma_f32_16x16x32_bf16(AH[ks], bh, acc, 0, 0, 0);
            acc = __builtin_amdgcn_mfma_f32_16x16x32_bf16(AL[ks], bh, acc, 0, 0, 0);
            acc = __builtin_amdgcn_mfma_f32_16x16x32_bf16(AH[ks], bl, acc, 0, 0, 0);
        }
#pragma unroll
        for (int r2 = 0; r2 < 4; ++r2) {            // C/D: col=lane&15, row=(lane>>4)*4+reg
            int rA = rbase + r2;
            float o = acc[r2];
            if (S) o -= S[(size_t)rA*128 + cB];
            Y[(size_t)rA*128 + cB] = o;
        }
    }
}

// ---------------- gather attention: 4 rows/wave, 16 lanes x 8 dims per row ----------------
__global__ __launch_bounds__(512) void attn_kernel(
    const float* __restrict__ Q,  const float* __restrict__ GK, const float* __restrict__ GV,
    const float* __restrict__ BASE, const float* __restrict__ bv,
    const int* __restrict__ idx, float* __restrict__ outp, float* __restrict__ x2out,
    ushort* __restrict__ xh, ushort* __restrict__ xl)
{
    int tid = threadIdx.x;
    int lane = tid & 63, wave = tid >> 6;
    int xcd = blockIdx.x & 7, sub = blockIdx.x >> 3;     // grid 512; XCD pair owns a batch
    int batch = xcd >> 1;
    int band = sub*2 + (xcd & 1);                        // 0..127
    int rgrp = lane >> 4;
    int dimg = lane & 15;
    int rib = band*32 + wave*4 + rgrp;
    int row = batch*NN + rib;
    int d0 = dimg*8;
    int gbase = lane & 48;
    const float* GKb = GK + (size_t)batch*NN*NC;
    const float* GVb = GV + (size_t)batch*NN*NC;

    float4 q0 = *(const float4*)&Q[(size_t)row*NC + d0];
    float4 q1 = *(const float4*)&Q[(size_t)row*NC + d0 + 4];
    int jv = idx[row*16 + dimg];

    float sc[16];
#pragma unroll
    for (int k = 0; k < 16; ++k) {
        int j = __shfl(jv, gbase + k, 64);
        const float* gk = &GKb[(size_t)j*NC + d0];
        float4 g0 = *(const float4*)gk;
        float4 g1 = *(const float4*)(gk + 4);
        float p = fmaf(q0.x, g0.x, fmaf(q0.y, g0.y, fmaf(q0.z, g0.z, fmaf(q0.w, g0.w,
                  fmaf(q1.x, g1.x, fmaf(q1.y, g1.y, fmaf(q1.z, g1.z, q1.w*g1.w)))))));
#pragma unroll
        for (int off = 1; off < 16; off <<= 1) p += __shfl_xor(p, off, 64);
        sc[k] = p * SCALE_F;
    }
    float m = sc[0];
#pragma unroll
    for (int k = 1; k < 16; ++k) m = fmaxf(m, sc[k]);
    float wsum = 0.f, w[16];
#pragma unroll
    for (int k = 0; k < 16; ++k) { w[k] = expf(sc[k] - m); wsum += w[k]; }
    float inv = 1.f / wsum;

    float4 a0 = {0.f,0.f,0.f,0.f}, a1 = {0.f,0.f,0.f,0.f};
#pragma unroll
    for (int k = 0; k < 16; ++k) {
        int j = __shfl(jv, gbase + k, 64);
        const float* gv = &GVb[(size_t)j*NC + d0];
        float4 v0 = *(const float4*)gv;
        float4 v1 = *(const float4*)(gv + 4);
        float a = w[k] * inv;
        a0.x = fmaf(a, v0.x, a0.x); a0.y = fmaf(a, v0.y, a0.y);
        a0.z = fmaf(a, v0.z, a0.z); a0.w = fmaf(a, v0.w, a0.w);
        a1.x = fmaf(a, v1.x, a1.x); a1.y = fmaf(a, v1.y, a1.y);
        a1.z = fmaf(a, v1.z, a1.z); a1.w = fmaf(a, v1.w, a1.w);
    }
    float4 b0 = *(const float4*)&BASE[(size_t)row*NC + d0];
    float4 b1 = *(const float4*)&BASE[(size_t)row*NC + d0 + 4];
    float4 c0 = *(const float4*)&bv[d0];
    float4 c1 = *(const float4*)&bv[d0 + 4];
    a0.x += b0.x + c0.x; a0.y += b0.y + c0.y; a0.z += b0.z + c0.z; a0.w += b0.w + c0.w;
    a1.x += b1.x + c1.x; a1.y += b1.y + c1.y; a1.z += b1.z + c1.z; a1.w += b1.w + c1.w;
    *(float4*)&outp[(size_t)row*NC + d0]     = a0;
    *(float4*)&outp[(size_t)row*NC + d0 + 4] = a1;

    if (x2out != nullptr) {
        float x2 = fmaf(a0.x, a0.x, fmaf(a0.y, a0.y, fmaf(a0.z, a0.z, fmaf(a0.w, a0.w,
                   fmaf(a1.x, a1.x, fmaf(a1.y, a1.y, fmaf(a1.z, a1.z, a1.w*a1.w)))))));
#pragma unroll
        for (int off = 1; off < 16; off <<= 1) x2 += __shfl_xor(x2, off, 64);
        if (dimg == 0) x2out[row] = x2;
    }
    if (xh != nullptr) {
        ushort h0 = f2bf(a0.x), h1 = f2bf(a0.y), h2 = f2bf(a0.z), h3 = f2bf(a0.w);
        ushort h4 = f2bf(a1.x), h5 = f2bf(a1.y), h6 = f2bf(a1.z), h7 = f2bf(a1.w);
        uint4 ph;
        ph.x = (unsigned)h0 | ((unsigned)h1 << 16);
        ph.y = (unsigned)h2 | ((unsigned)h3 << 16);
        ph.z = (unsigned)h4 | ((unsigned)h5 << 16);
        ph.w = (unsigned)h6 | ((unsigned)h7 << 16);
        *(uint4*)&xh[(size_t)row*NC + d0] = ph;
        ushort l0 = f2bf(a0.x - bf2f(h0)), l1 = f2bf(a0.y - bf2f(h1));
        ushort l2 = f2bf(a0.z - bf2f(h2)), l3 = f2bf(a0.w - bf2f(h3));
        ushort l4 = f2bf(a1.x - bf2f(h4)), l5 = f2bf(a1.y - bf2f(h5));
        ushort l6 = f2bf(a1.z - bf2f(h6)), l7 = f2bf(a1.w - bf2f(h7));
        uint4 pl;
        pl.x = (unsigned)l0 | ((unsigned)l1 << 16);
        pl.y = (unsigned)l2 | ((unsigned)l3 << 16);
        pl.z = (unsigned)l4 | ((unsigned)l5 << 16);
        pl.w = (unsigned)l6 | ((unsigned)l7 << 16);
        *(uint4*)&xl[(size_t)row*NC + d0] = pl;
    }
}

// ---------------- KNN stage 2: 3-term split-bf16 MFMA Gram + compacted dense top-16 ----------------
// ROUND-8 PROVEN CONFIG (179 us, VGPR 64, occ 43%): full 4096-col sweep, 32-row bands,
// grid 512, LDS 58 KB (2 blocks/CU), direct idxout write. Half-sweep variants (R9-R12)
// all regressed: extra live state tips the 64-VGPR wave-slot cliff (m69) or spills.
#define SCAN_STEP(CP, X2S, REFRESH) do { \
    float4 dd = *(const float4*)&DT[dtrd]; \
    float4 xx = *(const float4*)&(X2S)[slotl*4]; \
    float d2q0 = fmaf(-2.f, dd.x, xx.x); \
    float d2q1 = fmaf(-2.f, dd.y, xx.y); \
    float d2q2 = fmaf(-2.f, dd.z, xx.z); \
    float d2q3 = fmaf(-2.f, dd.w, xx.w); \
    bool p0 = d2q0 <= Trow, p1 = d2q1 <= Trow, p2 = d2q2 <= Trow, p3 = d2q3 <= Trow; \
    if (__ballot(p0 | p1 | p2 | p3)) { \
        unsigned g0 = (unsigned)(__ballot(p0) >> grpsh) & 0xFFFFu; \
        unsigned g1 = (unsigned)(__ballot(p1) >> grpsh) & 0xFFFFu; \
        unsigned g2 = (unsigned)(__ballot(p2) >> grpsh) & 0xFFFFu; \
        unsigned g3 = (unsigned)(__ballot(p3) >> grpsh) & 0xFFFFu; \
        int c0n = __popc(g0), c1n = __popc(g1), c2n = __popc(g2), c3n = __popc(g3); \
        int total = c0n + c1n + c2n + c3n; \
        if (total <= 32) { \
            if (p0) BUF[srow][__popc(g0 & lowm)]             = mkkey(d2q0, (CP) + slotl*4 + 0); \
            if (p1) BUF[srow][c0n + __popc(g1 & lowm)]       = mkkey(d2q1, (CP) + slotl*4 + 1); \
            if (p2) BUF[srow][c0n + c1n + __popc(g2 & lowm)] = mkkey(d2q2, (CP) + slotl*4 + 2); \
            if (p3) BUF[srow][c0n + c1n + c2n + __popc(g3 & lowm)] = mkkey(d2q3, (CP) + slotl*4 + 3); \
            if (slotl < total) { \
                unsigned long long k = BUF[srow][slotl]; \
                if (k < K15) INSERT16K(k); \
            } \
            if (16 + slotl < total) { \
                unsigned long long k = BUF[srow][16 + slotl]; \
                if (k < K15) INSERT16K(k); \
            } \
        } else { \
            unsigned long long kq; \
            if (p0) { kq = mkkey(d2q0, (CP) + slotl*4 + 0); if (kq < K15) INSERT16K(kq); } \
            if (p1) { kq = mkkey(d2q1, (CP) + slotl*4 + 1); if (kq < K15) INSERT16K(kq); } \
            if (p2) { kq = mkkey(d2q2, (CP) + slotl*4 + 2); if (kq < K15) INSERT16K(kq); } \
            if (p3) { kq = mkkey(d2q3, (CP) + slotl*4 + 3); if (kq < K15) INSERT16K(kq); } \
        } \
    } \
    if (REFRESH) { \
        unsigned long long tk = K15; \
        _Pragma("unroll") \
        for (int off = 1; off < 16; off <<= 1) { \
            unsigned long long o = __shfl_xor(tk, off, 64); \
            tk = (o < tk) ? o : tk; \
        } \
        unsigned uu = (unsigned)(tk >> 32); \
        uu = (uu > 0xFF800000u) ? 0xFF800000u : uu; \
        uu = (uu & 0x80000000u) ? (uu ^ 0x80000000u) : ~uu; \
        Trow = __uint_as_float(uu); \
    } \
} while (0)

__global__ __launch_bounds__(512, 2) void knn2_kernel(const ushort* __restrict__ XHg,
                                                      const ushort* __restrict__ XLg,
                                                      const float* __restrict__ x2g,
                                                      int* __restrict__ idxout)
{
    __shared__ __align__(16) ushort XCH[64*128];        // 16 KB [c][d ^ ((c&7)<<3)]
    __shared__ __align__(16) ushort XCL[64*128];        // 16 KB
    __shared__ __align__(16) float  DT[32*64];          //  8 KB rotation swizzle
    __shared__ unsigned long long   BUF[32][33];        //  8.25 KB survivor buffers (cap 32)
    __shared__ __align__(16) float  X2T[2][64];         //  0.5 KB
    int tid = threadIdx.x;
    int lane = tid & 63, wave = tid >> 6;
    int xcd = blockIdx.x & 7, sub = blockIdx.x >> 3;    // grid 512
    int batch = xcd >> 1;
    int band = sub*2 + (xcd & 1);                       // 0..127
    const ushort* XHb = XHg + (size_t)batch*NN*NC;
    const ushort* XLb = XLg + (size_t)batch*NN*NC;
    const float*  x2b = x2g + (size_t)batch*NN;
    int r0 = band*32;

    int rowblk = wave & 1, colblk = wave >> 1;
    int dbase = (lane >> 4) * 8;
    int gr = r0 + rowblk*16 + (lane & 15);
    bf16x8 AH[4], AL[4];
#pragma unroll
    for (int ks = 0; ks < 4; ++ks) {
        AH[ks] = *(const bf16x8*)&XHb[(size_t)gr*NC + ks*32 + dbase];
        AL[ks] = *(const bf16x8*)&XLb[(size_t)gr*NC + ks*32 + dbase];
    }
    int cB = colblk*16 + (lane & 15);
    int colw = cB;

    int srow = tid >> 4, slotl = tid & 15;
    int grpsh = lane & 48;
    unsigned lowm = (1u << slotl) - 1u;
    int dtrd = srow*64 + ((slotl*4 + 4*srow) & 63);
    float Trow = INFINITY;
    DECL16K

    for (int t = 0; t < 64; ++t) {
        int c0 = t*64;
        __syncthreads();                                // MFMA(t-1) done: DT ready, XC free
        // stage hi+lo col tiles with XOR swizzle
#pragma unroll
        for (int i = 0; i < 2; ++i) {
            int qq = tid + 512*i;
            int c = qq >> 4, d8 = qq & 15;
            int widx = c*128 + ((d8*8) ^ ((c & 7) << 3));
            *(uint4*)&XCH[widx] = *(const uint4*)&XHb[(size_t)(c0 + c)*NC + d8*8];
            *(uint4*)&XCL[widx] = *(const uint4*)&XLb[(size_t)(c0 + c)*NC + d8*8];
        }
        if (tid < 64) X2T[t & 1][tid] = x2b[c0 + tid];
        if (t > 0) {
            const float* x2s = X2T[(t - 1) & 1];
            SCAN_STEP(c0 - 64, x2s, 1);
        }
        __syncthreads();                                // staging visible; DT free
        // MFMA: one 16x16 tile per wave, 3-term split-bf16 (hh + lh + hl), K=128
        f32x4 acc = {0.f, 0.f, 0.f, 0.f};
#pragma unroll
        for (int ks = 0; ks < 4; ++ks) {
            int bidx = cB*128 + ((ks*32 + dbase) ^ ((cB & 7) << 3));
            bf16x8 bh = *(const bf16x8*)&XCH[bidx];
            bf16x8 bl = *(const bf16x8*)&XCL[bidx];
            acc = __builtin_amdgcn_mfma_f32_16x16x32_bf16(AH[ks], bh, acc, 0, 0, 0);
            acc = __builtin_amdgcn_mfma_f32_16x16x32_bf16(AL[ks], bh, acc, 0, 0, 0);
            acc = __builtin_amdgcn_mfma_f32_16x16x32_bf16(AH[ks], bl, acc, 0, 0, 0);
        }
#pragma unroll
        for (int r2 = 0; r2 < 4; ++r2) {                // C/D: col=lane&15, row=(lane>>4)*4+reg
            int rA = rowblk*16 + (lane >> 4)*4 + r2;
            DT[rA*64 + (((colw & ~3) + 4*rA) & 63) + (colw & 3)] = acc[r2];
        }
    }
    __syncthreads();
    {   // scan last tile (t=63's DT), parity 63&1 = 1
        const float* x2s = X2T[1];
        SCAN_STEP(63*64, x2s, 0);
    }
    // per-row 16-lane pop-merge; emit final top-16 indices
    int grow = batch*NN + r0 + srow;
    for (int tt = 0; tt < 16; ++tt) {
        unsigned long long g = K0;
#pragma unroll
        for (int off = 1; off < 16; off <<= 1) {
            unsigned long long o = __shfl_xor(g, off, 64);
            g = (o < g) ? o : g;
        }
        bool win = (K0 == g);
        if (win) idxout[grow*16 + tt] = (int)(unsigned)(g & 0xFFFFFFFFull);
        POP16K(win);
    }
}

// ---------------- final fused LN / linear / LN / transpose ----------------
__global__ __launch_bounds__(256) void final_kernel(
    const float* __restrict__ tgt, const float* __restrict__ att,
    const float* __restrict__ Wl, const float* __restrict__ bl,
    const float* __restrict__ g0, const float* __restrict__ b0,
    const float* __restrict__ g1, const float* __restrict__ b1,
    float* __restrict__ outp)
{
    __shared__ float WL[128*128];
    int tid = threadIdx.x;
    for (int f = tid; f < 16384; f += 256) {
        int c = f >> 7, d = f & 127;
        WL[d*128 + (c ^ (d & 14))] = Wl[f];
    }
    __syncthreads();
    int lane = tid & 63, wave = tid >> 6;
    float2 gg0 = *(const float2*)&g0[2*lane];
    float2 bb0 = *(const float2*)&b0[2*lane];
    float2 gg1 = *(const float2*)&g1[2*lane];
    float2 bb1 = *(const float2*)&b1[2*lane];
    float2 bl2 = *(const float2*)&bl[2*lane];
    for (int it = 0; it < 4; ++it) {
        int row0 = blockIdx.x*64 + it*16 + wave*4;
        float2 tg[4];
        float lnx[4], lny[4];
#pragma unroll
        for (int r = 0; r < 4; ++r) {
            int row = row0 + r;
            tg[r] = *(const float2*)&tgt[row*128 + 2*lane];
            float2 at = *(const float2*)&att[row*128 + 2*lane];
            float ox = tg[r].x + at.x, oy = tg[r].y + at.y;
            float s = ox + oy;
#pragma unroll
            for (int off = 1; off < 64; off <<= 1) s += __shfl_xor(s, off, 64);
            float mu = s * (1.f/128.f);
            float dx = ox - mu, dy = oy - mu;
            float vv = fmaf(dx, dx, dy*dy);
#pragma unroll
            for (int off = 1; off < 64; off <<= 1) vv += __shfl_xor(vv, off, 64);
            float rstd = rsqrtf(vv * (1.f/128.f) + 1e-5f);
            lnx[r] = dx * rstd * gg0.x + bb0.x;
            lny[r] = dy * rstd * gg0.y + bb0.y;
        }
        float2 acc[4];
#pragma unroll
        for (int r = 0; r < 4; ++r) { acc[r].x = 0.f; acc[r].y = 0.f; }
#pragma unroll 8
        for (int dh = 0; dh < 64; ++dh) {
            int cidx = (2*lane) ^ ((2*dh) & 14);
            float2 wa = *(const float2*)&WL[(2*dh)*128 + cidx];
            float2 wb = *(const float2*)&WL[(2*dh+1)*128 + cidx];
#pragma unroll
            for (int r = 0; r < 4; ++r) {
                float xa = rl_f(lnx[r], dh);
                float xb = rl_f(lny[r], dh);
                acc[r].x = fmaf(xa, wa.x, acc[r].x);
                acc[r].y = fmaf(xa, wa.y, acc[r].y);
                acc[r].x = fmaf(xb, wb.x, acc[r].x);
                acc[r].y = fmaf(xb, wb.y, acc[r].y);
            }
        }
#pragma unroll
        for (int r = 0; r < 4; ++r) {
            int row = row0 + r;
            float zx = tg[r].x + acc[r].x + bl2.x;
            float zy = tg[r].y + acc[r].y + bl2.y;
            float s = zx + zy;
#pragma unroll
            for (int off = 1; off < 64; off <<= 1) s += __shfl_xor(s, off, 64);
            float mu = s * (1.f/128.f);
            float dx = zx - mu, dy = zy - mu;
            float vv = fmaf(dx, dx, dy*dy);
#pragma unroll
            for (int off = 1; off < 64; off <<= 1) vv += __shfl_xor(vv, off, 64);
            float rstd = rsqrtf(vv * (1.f/128.f) + 1e-5f);
            float2 res;
            res.x = dx * rstd * gg1.x + bb1.x;
            res.y = dy * rstd * gg1.y + bb1.y;
            int b = row >> 12, n = row & 4095;
            *(float2*)&outp[((size_t)n*NB + b)*128 + 2*lane] = res;
        }
    }
}

extern "C" void kernel_launch(void* const* d_in, const int* in_sizes, int n_in,
                              void* d_out, int out_size, void* d_ws, size_t ws_size,
                              hipStream_t stream)
{
    (void)in_sizes; (void)n_in; (void)out_size; (void)ws_size;
    const float* src = (const float*)d_in[0];
    const float* tgt = (const float*)d_in[1];
    const float* Wq0 = (const float*)d_in[2];
    const float* Wk0 = (const float*)d_in[3];
    const float* Wv0 = (const float*)d_in[4];
    const float* Wq1 = (const float*)d_in[5];
    const float* Wk1 = (const float*)d_in[6];
    const float* Wv1 = (const float*)d_in[7];
    const float* Wp0 = (const float*)d_in[8];
    const float* bp0 = (const float*)d_in[9];
    const float* Wp1 = (const float*)d_in[10];
    const float* bp1 = (const float*)d_in[11];
    const float* Wl  = (const float*)d_in[12];
    const float* bl  = (const float*)d_in[13];
    const float* g0  = (const float*)d_in[14];
    const float* b0  = (const float*)d_in[15];
    const float* g1  = (const float*)d_in[16];
    const float* b1  = (const float*)d_in[17];
    float* out = (float*)d_out;

    float* A0   = (float*)d_ws;                  // Ybase: A0..A4 contiguous
    float* A1   = A0 + 2097152;
    float* A2   = A1 + 2097152;
    float* A3   = A2 + 2097152;
    float* A4   = A3 + 2097152;
    float* OUT1 = A4 + 2097152;
    int*   IDX1 = (int*)(OUT1 + 2097152);
    int*   IDX2 = IDX1 + NROWS*16;
    float* X2G  = (float*)(IDX2 + NROWS*16);
    float* WKP0 = X2G + NROWS;
    float* BK0  = WKP0 + 384;
    float* WVP0 = BK0 + 128;
    float* BV0  = WVP0 + 384;
    float* WKD  = BV0 + 128;
    float* MV1  = WKD + 16384;
    float* WVD  = MV1 + 16384;
    float* BV1  = WVD + 16384;
    ushort* WSH = (ushort*)(BV1 + 128);          // 7 x 16384 bf16-hi weight slots
    ushort* WSL = WSH + 7*16384;                 // 7 x 16384 bf16-lo
    ushort* XH  = WSL + 7*16384;                 // 4 MB (tgt-split, then OUT1-split)
    ushort* XL  = XH + (size_t)NROWS*NC;         // 4 MB

    combo_small<<<dim3(2), dim3(512), 0, stream>>>(Wk0, Wv0, Wp0, bp0, WKP0, BK0, WVP0, BV0);
    combo_big<<<dim3(129), dim3(256), 0, stream>>>(Wk1, Wv1, Wp1, bp1, WKD, MV1, WVD, BV1);
    // weight slots: 0=Wq0 1=Wk0 2=Wv0 | 3=Wq1 4=WKD 5=WVD 6=MV1
    split7<<<dim3(64, 7), dim3(256), 0, stream>>>(Wq0, Wk0, Wv0, Wq1, WKD, WVD, MV1, WSH, WSL);
    srcproj<<<dim3(8192), dim3(256), 0, stream>>>(src, WKP0, WVP0, A3, A4);
    splitx<<<dim3(1024), dim3(256), 0, stream>>>(tgt, XH, XL);      // XH/XL = tgt split
    knn1_kernel<<<dim3(4096), dim3(256), 0, stream>>>(src, IDX1);
    // stage-1 GEMMs: A0 = tgt@Wq0^T ; A1 = tgt@Wk0^T - srcKp(A3) ; A2 = tgt@Wv0^T - srcVp(A4)
    gemm128<<<dim3(256, 3), dim3(256), 0, stream>>>(XH, XL, WSH, WSL, A3, A4, A0);
    attn_kernel<<<dim3(512), dim3(512), 0, stream>>>(A0, A1, A2, A4, BV0, IDX1, OUT1, X2G, XH, XL);
    knn2_kernel<<<dim3(512), dim3(512), 0, stream>>>(XH, XL, X2G, IDX2);
    // stage-2 GEMMs: A0 = Q1 ; A1 = GK2 ; A2 = GV2 ; A3 = BASE2 (X@MV1^T)
    gemm128<<<dim3(256, 4), dim3(256), 0, stream>>>(XH, XL, WSH + 3*16384, WSL + 3*16384,
                                                    nullptr, nullptr, A0);
    attn_kernel<<<dim3(512), dim3(512), 0, stream>>>(A0, A1, A2, A3, BV1, IDX2, OUT1, nullptr, nullptr, nullptr);
    final_kernel<<<dim3(256), dim3(256), 0, stream>>>(tgt, OUT1, Wl, bl, g0, b0, g1, b1, out);
}

// Round 14
// 426.427 us; speedup vs baseline: 1.4602x; 1.2913x over previous
//
#include <hip/hip_runtime.h>
#include <math.h>

#define NB 4
#define NN 4096
#define NC 128
#define NROWS (NB*NN)
#define SCALE_F 0.08838834764831845f   // 1/sqrt(128)

using bf16x8 = __attribute__((ext_vector_type(8))) short;
using f32x4  = __attribute__((ext_vector_type(4))) float;

__device__ __forceinline__ float rl_f(float x, int l) {
    return __int_as_float(__builtin_amdgcn_readlane(__float_as_int(x), l));
}
__device__ __forceinline__ ushort f2bf(float x) {          // fp32 -> bf16 RNE
    unsigned u = __float_as_uint(x);
    return (ushort)((u + 0x7FFF + ((u >> 16) & 1)) >> 16);
}
__device__ __forceinline__ float bf2f(ushort b) { return __uint_as_float(((unsigned)b) << 16); }

// monotone key: (order-preserving float bits) << 32 | index  — lex (value, idx) asc
__device__ __forceinline__ unsigned long long mkkey(float d2, int idx) {
    unsigned u = __float_as_uint(d2);
    u ^= ((unsigned)((int)u >> 31)) | 0x80000000u;
    return ((unsigned long long)u << 32) | (unsigned)idx;
}

// ---- 16-deep sorted (ascending) float register lists (knn1) ----
#define DECL16V \
    float v0=INFINITY,v1=INFINITY,v2=INFINITY,v3=INFINITY,v4=INFINITY,v5=INFINITY,v6=INFINITY,v7=INFINITY, \
          v8=INFINITY,v9=INFINITY,v10=INFINITY,v11=INFINITY,v12=INFINITY,v13=INFINITY,v14=INFINITY,v15=INFINITY;

#define INSERT16V(dv) do { float d_=(dv); \
    bool m0=d_<v0,m1=d_<v1,m2=d_<v2,m3=d_<v3,m4=d_<v4,m5=d_<v5,m6=d_<v6,m7=d_<v7, \
         m8=d_<v8,m9=d_<v9,m10=d_<v10,m11=d_<v11,m12=d_<v12,m13=d_<v13,m14=d_<v14,m15=d_<v15; \
    v15=m14?v14:(m15?d_:v15); v14=m13?v13:(m14?d_:v14); v13=m12?v12:(m13?d_:v13); v12=m11?v11:(m12?d_:v12); \
    v11=m10?v10:(m11?d_:v11); v10=m9?v9:(m10?d_:v10); v9 =m8?v8:(m9?d_:v9);  v8 =m7?v7:(m8?d_:v8); \
    v7 =m6?v6:(m7?d_:v7);   v6 =m5?v5:(m6?d_:v6);   v5 =m4?v4:(m5?d_:v5);  v4 =m3?v3:(m4?d_:v4); \
    v3 =m2?v2:(m3?d_:v3);   v2 =m1?v1:(m2?d_:v2);   v1 =m0?v0:(m1?d_:v1);  v0 =m0?d_:v0; } while(0)

#define POP16V(p) do { bool p_=(p); \
    v0=p_?v1:v0; v1=p_?v2:v1; v2=p_?v3:v2; v3=p_?v4:v3; v4=p_?v5:v4; v5=p_?v6:v5; v6=p_?v7:v6; v7=p_?v8:v7; \
    v8=p_?v9:v8; v9=p_?v10:v9; v10=p_?v11:v10; v11=p_?v12:v11; v12=p_?v13:v12; v13=p_?v14:v13; v14=p_?v15:v14; \
    v15=p_?INFINITY:v15; } while(0)

// ---- 16-deep sorted (ascending) u64-key register lists (knn2) ----
#define KMAX16 0xFFFFFFFFFFFFFFFFull
#define DECL16K \
    unsigned long long K0=KMAX16,K1=KMAX16,K2=KMAX16,K3=KMAX16,K4=KMAX16,K5=KMAX16,K6=KMAX16,K7=KMAX16, \
                       K8=KMAX16,K9=KMAX16,K10=KMAX16,K11=KMAX16,K12=KMAX16,K13=KMAX16,K14=KMAX16,K15=KMAX16;

#define INSERT16K(kv) do { unsigned long long k_=(kv); \
    bool m0=k_<K0,m1=k_<K1,m2=k_<K2,m3=k_<K3,m4=k_<K4,m5=k_<K5,m6=k_<K6,m7=k_<K7, \
         m8=k_<K8,m9=k_<K9,m10=k_<K10,m11=k_<K11,m12=k_<K12,m13=k_<K13,m14=k_<K14,m15=k_<K15; \
    K15=m14?K14:(m15?k_:K15); K14=m13?K13:(m14?k_:K14); K13=m12?K12:(m13?k_:K13); K12=m11?K11:(m12?k_:K12); \
    K11=m10?K10:(m11?k_:K11); K10=m9?K9:(m10?k_:K10);   K9 =m8?K8:(m9?k_:K9);    K8 =m7?K7:(m8?k_:K8); \
    K7 =m6?K6:(m7?k_:K7);     K6 =m5?K5:(m6?k_:K6);     K5 =m4?K4:(m5?k_:K5);    K4 =m3?K3:(m4?k_:K4); \
    K3 =m2?K2:(m3?k_:K3);     K2 =m1?K1:(m2?k_:K2);     K1 =m0?K0:(m1?k_:K1);    K0 =m0?k_:K0; } while(0)

#define POP16K(p) do { bool p_=(p); \
    K0=p_?K1:K0; K1=p_?K2:K1; K2=p_?K3:K2; K3=p_?K4:K3; K4=p_?K5:K4; K5=p_?K6:K5; K6=p_?K7:K6; K7=p_?K8:K7; \
    K8=p_?K9:K8; K9=p_?K10:K9; K10=p_?K11:K10; K11=p_?K12:K11; K12=p_?K13:K12; K13=p_?K14:K13; K14=p_?K15:K14; \
    K15=p_?KMAX16:K15; } while(0)

// ---------------- tiny weight combos ----------------
__global__ void combo_small(const float* __restrict__ Wk0, const float* __restrict__ Wv0,
                            const float* __restrict__ Wp0, const float* __restrict__ bp0,
                            float* __restrict__ WKP0, float* __restrict__ BK0,
                            float* __restrict__ WVP0, float* __restrict__ BV0)
{
    int task = blockIdx.x * 512 + threadIdx.x;
    if (task >= 1024) return;
    int mat = task >> 9; int rem = task & 511;
    int c = rem >> 2, t = rem & 3;
    const float* W = mat ? Wv0 : Wk0;
    float s = 0.f;
    if (t < 3) {
        for (int d = 0; d < 128; ++d) s = fmaf(W[c*128+d], Wp0[d*3+t], s);
        (mat ? WVP0 : WKP0)[c*3+t] = s;
    } else {
        for (int d = 0; d < 128; ++d) s = fmaf(W[c*128+d], bp0[d], s);
        (mat ? BV0 : BK0)[c] = s;
    }
}

// WKD = Wk1 - Wk1@Wp1 ; MV1 = Wv1@Wp1 ; WVD = Wv1 - MV1 ; BV1 = Wv1@bp1
__global__ void combo_big(const float* __restrict__ Wk1, const float* __restrict__ Wv1,
                          const float* __restrict__ Wp1, const float* __restrict__ bp1,
                          float* __restrict__ WKD, float* __restrict__ MV1,
                          float* __restrict__ WVD, float* __restrict__ BV1)
{
    int task = blockIdx.x * 256 + threadIdx.x;   // grid 129 x 256
    if (task >= 32896) return;
    if (task < 32768) {
        int mat = task >> 14; int rem = task & 16383;
        int c = rem >> 7, tcol = rem & 127;
        const float* W = mat ? Wv1 : Wk1;
        float s = 0.f;
        for (int d = 0; d < 128; ++d) s = fmaf(W[c*128+d], Wp1[d*128+tcol], s);
        if (mat) { MV1[rem] = s; WVD[rem] = Wv1[rem] - s; }
        else     { WKD[rem] = Wk1[rem] - s; }
    } else {
        int c = task - 32768;
        float s = 0.f;
        for (int d = 0; d < 128; ++d) s = fmaf(Wv1[c*128+d], bp1[d], s);
        BV1[c] = s;
    }
}

// split 7 weight matrices (16384 elems each) into contiguous bf16 hi/lo slots
__global__ void split7(const float* __restrict__ W0, const float* __restrict__ W1,
                       const float* __restrict__ W2, const float* __restrict__ W3,
                       const float* __restrict__ W4, const float* __restrict__ W5,
                       const float* __restrict__ W6,
                       ushort* __restrict__ WSH, ushort* __restrict__ WSL)
{
    int y = blockIdx.y;
    const float* W;
    switch (y) {
        case 0: W = W0; break; case 1: W = W1; break; case 2: W = W2; break;
        case 3: W = W3; break; case 4: W = W4; break; case 5: W = W5; break;
        default: W = W6; break;
    }
    int i = blockIdx.x*256 + threadIdx.x;          // grid.x = 64
    float v = W[i];
    ushort h = f2bf(v);
    WSH[y*16384 + i] = h;
    WSL[y*16384 + i] = f2bf(v - bf2f(h));
}

// split fp32 activation matrix into bf16 hi/lo (8 elems/thread)
__global__ void splitx(const float* __restrict__ X, ushort* __restrict__ XH,
                       ushort* __restrict__ XL)
{
    int i = (blockIdx.x*256 + threadIdx.x) * 8;    // grid 1024
    float4 a = *(const float4*)&X[i];
    float4 b = *(const float4*)&X[i+4];
    ushort h0=f2bf(a.x),h1=f2bf(a.y),h2=f2bf(a.z),h3=f2bf(a.w);
    ushort h4=f2bf(b.x),h5=f2bf(b.y),h6=f2bf(b.z),h7=f2bf(b.w);
    uint4 ph;
    ph.x=(unsigned)h0|((unsigned)h1<<16); ph.y=(unsigned)h2|((unsigned)h3<<16);
    ph.z=(unsigned)h4|((unsigned)h5<<16); ph.w=(unsigned)h6|((unsigned)h7<<16);
    *(uint4*)&XH[i] = ph;
    ushort l0=f2bf(a.x-bf2f(h0)),l1=f2bf(a.y-bf2f(h1)),l2=f2bf(a.z-bf2f(h2)),l3=f2bf(a.w-bf2f(h3));
    ushort l4=f2bf(b.x-bf2f(h4)),l5=f2bf(b.y-bf2f(h5)),l6=f2bf(b.z-bf2f(h6)),l7=f2bf(b.w-bf2f(h7));
    uint4 pl;
    pl.x=(unsigned)l0|((unsigned)l1<<16); pl.y=(unsigned)l2|((unsigned)l3<<16);
    pl.z=(unsigned)l4|((unsigned)l5<<16); pl.w=(unsigned)l6|((unsigned)l7<<16);
    *(uint4*)&XL[i] = pl;
}

__global__ void srcproj(const float* __restrict__ src, const float* __restrict__ WKP0,
                        const float* __restrict__ WVP0,
                        float* __restrict__ srcKp, float* __restrict__ srcVp)
{
    int gid = blockIdx.x * 256 + threadIdx.x;
    int i = gid >> 7, c = gid & 127;
    float s0 = src[i*3+0], s1 = src[i*3+1], s2 = src[i*3+2];
    srcKp[gid] = fmaf(s0, WKP0[c*3+0], fmaf(s1, WKP0[c*3+1], s2*WKP0[c*3+2]));
    srcVp[gid] = fmaf(s0, WVP0[c*3+0], fmaf(s1, WVP0[c*3+1], s2*WVP0[c*3+2]));
}

// ---------------- KNN stage 1 (3-D), one wave per row, value-threshold 2-pass ----------------
__global__ __launch_bounds__(256) void knn1_kernel(const float* __restrict__ src,
                                                   int* __restrict__ idxout)
{
    int lane = threadIdx.x & 63, wave = threadIdx.x >> 6;
    int b7 = blockIdx.x & 7, sub = blockIdx.x >> 3;
    int batch = b7 >> 1;
    int rib = (sub*2 + (b7 & 1))*4 + wave;
    int row = batch*NN + rib;
    const float* sb = src + batch*NN*3;
    float xi0 = sb[rib*3], xi1 = sb[rib*3+1], xi2 = sb[rib*3+2];

    DECL16V
    for (int it = 0; it < 64; ++it) {
        int j = it*64 + lane;
        float dx = xi0 - sb[j*3], dy = xi1 - sb[j*3+1], dz = xi2 - sb[j*3+2];
        float d2 = fmaf(dx, dx, fmaf(dy, dy, dz*dz));
        if (d2 < v15) INSERT16V(d2);
    }
    float T = INFINITY;
    for (int t = 0; t < 16; ++t) {
        float g = v0;
#pragma unroll
        for (int off = 1; off < 64; off <<= 1) g = fminf(g, __shfl_xor(g, off, 64));
        unsigned long long b = __ballot(v0 == g);
        int f = __ffsll((long long)b) - 1;
        POP16V(lane == f);
        T = g;
    }
    unsigned long long below_mask = (lane == 63) ? 0x7fffffffffffffffull : ((1ull << lane) - 1ull);
    int base = 0;
    for (int it = 0; it < 64; ++it) {
        int j = it*64 + lane;
        float dx = xi0 - sb[j*3], dy = xi1 - sb[j*3+1], dz = xi2 - sb[j*3+2];
        float d2 = fmaf(dx, dx, fmaf(dy, dy, dz*dz));
        unsigned long long blt = __ballot(d2 < T);
        if (d2 < T) idxout[row*16 + base + __popcll(blt & below_mask)] = j;
        base += __popcll(blt);
    }
    for (int it = 0; it < 64 && base < 16; ++it) {
        int j = it*64 + lane;
        float dx = xi0 - sb[j*3], dy = xi1 - sb[j*3+1], dz = xi2 - sb[j*3+2];
        float d2 = fmaf(dx, dx, fmaf(dy, dy, dz*dz));
        unsigned long long beq = __ballot(d2 == T);
        int bel = __popcll(beq & below_mask);
        if (d2 == T && base + bel < 16) idxout[row*16 + base + bel] = j;
        base += __popcll(beq);
    }
}

// ---------------- split-bf16 MFMA GEMM: Y = X @ W^T (- S), X/W pre-split hi/lo ----------------
__global__ __launch_bounds__(256, 2) void gemm128(
    const ushort* __restrict__ XHg, const ushort* __restrict__ XLg,
    const ushort* __restrict__ WHb, const ushort* __restrict__ WLb,
    const float* __restrict__ S1, const float* __restrict__ S2,
    float* __restrict__ Ybase)
{
    __shared__ __align__(16) ushort WHs[128*128];   // 32 KB [c][d ^ ((c&7)<<3)]
    __shared__ __align__(16) ushort WLs[128*128];   // 32 KB
    int tid = threadIdx.x, lane = tid & 63, wave = tid >> 6;
    int y = blockIdx.y;
    const ushort* WH = WHb + y*16384;
    const ushort* WL = WLb + y*16384;
    float* Y = Ybase + (size_t)y*2097152;
    const float* S = (y == 1) ? S1 : ((y == 2) ? S2 : nullptr);
#pragma unroll
    for (int i = 0; i < 8; ++i) {
        int q = tid + 256*i;
        int c = q >> 4, d8 = q & 15;
        int widx = c*128 + ((d8*8) ^ ((c & 7) << 3));
        *(uint4*)&WHs[widx] = *(const uint4*)&WH[c*128 + d8*8];
        *(uint4*)&WLs[widx] = *(const uint4*)&WL[c*128 + d8*8];
    }
    int r = blockIdx.x*64 + wave*16 + (lane & 15);
    int dbase = (lane >> 4) * 8;
    bf16x8 AH[4], AL[4];
#pragma unroll
    for (int ks = 0; ks < 4; ++ks) {
        AH[ks] = *(const bf16x8*)&XHg[(size_t)r*128 + ks*32 + dbase];
        AL[ks] = *(const bf16x8*)&XLg[(size_t)r*128 + ks*32 + dbase];
    }
    __syncthreads();
    int rbase = blockIdx.x*64 + wave*16 + (lane >> 4)*4;
#pragma unroll
    for (int cb = 0; cb < 8; ++cb) {
        int cB = cb*16 + (lane & 15);
        f32x4 acc = {0.f, 0.f, 0.f, 0.f};
#pragma unroll
        for (int ks = 0; ks < 4; ++ks) {
            int bidx = cB*128 + ((ks*32 + dbase) ^ ((cB & 7) << 3));
            bf16x8 bh = *(const bf16x8*)&WHs[bidx];
            bf16x8 bl = *(const bf16x8*)&WLs[bidx];
            acc = __builtin_amdgcn_mfma_f32_16x16x32_bf16(AH[ks], bh, acc, 0, 0, 0);
            acc = __builtin_amdgcn_mfma_f32_16x16x32_bf16(AL[ks], bh, acc, 0, 0, 0);
            acc = __builtin_amdgcn_mfma_f32_16x16x32_bf16(AH[ks], bl, acc, 0, 0, 0);
        }
#pragma unroll
        for (int r2 = 0; r2 < 4; ++r2) {            // C/D: col=lane&15, row=(lane>>4)*4+reg
            int rA = rbase + r2;
            float o = acc[r2];
            if (S) o -= S[(size_t)rA*128 + cB];
            Y[(size_t)rA*128 + cB] = o;
        }
    }
}

// ---------------- gather attention: 4 rows/wave, 16 lanes x 8 dims per row ----------------
__global__ __launch_bounds__(512) void attn_kernel(
    const float* __restrict__ Q,  const float* __restrict__ GK, const float* __restrict__ GV,
    const float* __restrict__ BASE, const float* __restrict__ bv,
    const int* __restrict__ idx, float* __restrict__ outp, float* __restrict__ x2out,
    ushort* __restrict__ xh, ushort* __restrict__ xl)
{
    int tid = threadIdx.x;
    int lane = tid & 63, wave = tid >> 6;
    int xcd = blockIdx.x & 7, sub = blockIdx.x >> 3;     // grid 512; XCD pair owns a batch
    int batch = xcd >> 1;
    int band = sub*2 + (xcd & 1);                        // 0..127
    int rgrp = lane >> 4;
    int dimg = lane & 15;
    int rib = band*32 + wave*4 + rgrp;
    int row = batch*NN + rib;
    int d0 = dimg*8;
    int gbase = lane & 48;
    const float* GKb = GK + (size_t)batch*NN*NC;
    const float* GVb = GV + (size_t)batch*NN*NC;

    float4 q0 = *(const float4*)&Q[(size_t)row*NC + d0];
    float4 q1 = *(const float4*)&Q[(size_t)row*NC + d0 + 4];
    int jv = idx[row*16 + dimg];

    float sc[16];
#pragma unroll
    for (int k = 0; k < 16; ++k) {
        int j = __shfl(jv, gbase + k, 64);
        const float* gk = &GKb[(size_t)j*NC + d0];
        float4 g0 = *(const float4*)gk;
        float4 g1 = *(const float4*)(gk + 4);
        float p = fmaf(q0.x, g0.x, fmaf(q0.y, g0.y, fmaf(q0.z, g0.z, fmaf(q0.w, g0.w,
                  fmaf(q1.x, g1.x, fmaf(q1.y, g1.y, fmaf(q1.z, g1.z, q1.w*g1.w)))))));
#pragma unroll
        for (int off = 1; off < 16; off <<= 1) p += __shfl_xor(p, off, 64);
        sc[k] = p * SCALE_F;
    }
    float m = sc[0];
#pragma unroll
    for (int k = 1; k < 16; ++k) m = fmaxf(m, sc[k]);
    float wsum = 0.f, w[16];
#pragma unroll
    for (int k = 0; k < 16; ++k) { w[k] = expf(sc[k] - m); wsum += w[k]; }
    float inv = 1.f / wsum;

    float4 a0 = {0.f,0.f,0.f,0.f}, a1 = {0.f,0.f,0.f,0.f};
#pragma unroll
    for (int k = 0; k < 16; ++k) {
        int j = __shfl(jv, gbase + k, 64);
        const float* gv = &GVb[(size_t)j*NC + d0];
        float4 v0 = *(const float4*)gv;
        float4 v1 = *(const float4*)(gv + 4);
        float a = w[k] * inv;
        a0.x = fmaf(a, v0.x, a0.x); a0.y = fmaf(a, v0.y, a0.y);
        a0.z = fmaf(a, v0.z, a0.z); a0.w = fmaf(a, v0.w, a0.w);
        a1.x = fmaf(a, v1.x, a1.x); a1.y = fmaf(a, v1.y, a1.y);
        a1.z = fmaf(a, v1.z, a1.z); a1.w = fmaf(a, v1.w, a1.w);
    }
    float4 b0 = *(const float4*)&BASE[(size_t)row*NC + d0];
    float4 b1 = *(const float4*)&BASE[(size_t)row*NC + d0 + 4];
    float4 c0 = *(const float4*)&bv[d0];
    float4 c1 = *(const float4*)&bv[d0 + 4];
    a0.x += b0.x + c0.x; a0.y += b0.y + c0.y; a0.z += b0.z + c0.z; a0.w += b0.w + c0.w;
    a1.x += b1.x + c1.x; a1.y += b1.y + c1.y; a1.z += b1.z + c1.z; a1.w += b1.w + c1.w;
    *(float4*)&outp[(size_t)row*NC + d0]     = a0;
    *(float4*)&outp[(size_t)row*NC + d0 + 4] = a1;

    if (x2out != nullptr) {
        float x2 = fmaf(a0.x, a0.x, fmaf(a0.y, a0.y, fmaf(a0.z, a0.z, fmaf(a0.w, a0.w,
                   fmaf(a1.x, a1.x, fmaf(a1.y, a1.y, fmaf(a1.z, a1.z, a1.w*a1.w)))))));
#pragma unroll
        for (int off = 1; off < 16; off <<= 1) x2 += __shfl_xor(x2, off, 64);
        if (dimg == 0) x2out[row] = x2;
    }
    if (xh != nullptr) {
        ushort h0 = f2bf(a0.x), h1 = f2bf(a0.y), h2 = f2bf(a0.z), h3 = f2bf(a0.w);
        ushort h4 = f2bf(a1.x), h5 = f2bf(a1.y), h6 = f2bf(a1.z), h7 = f2bf(a1.w);
        uint4 ph;
        ph.x = (unsigned)h0 | ((unsigned)h1 << 16);
        ph.y = (unsigned)h2 | ((unsigned)h3 << 16);
        ph.z = (unsigned)h4 | ((unsigned)h5 << 16);
        ph.w = (unsigned)h6 | ((unsigned)h7 << 16);
        *(uint4*)&xh[(size_t)row*NC + d0] = ph;
        ushort l0 = f2bf(a0.x - bf2f(h0)), l1 = f2bf(a0.y - bf2f(h1));
        ushort l2 = f2bf(a0.z - bf2f(h2)), l3 = f2bf(a0.w - bf2f(h3));
        ushort l4 = f2bf(a1.x - bf2f(h4)), l5 = f2bf(a1.y - bf2f(h5));
        ushort l6 = f2bf(a1.z - bf2f(h6)), l7 = f2bf(a1.w - bf2f(h7));
        uint4 pl;
        pl.x = (unsigned)l0 | ((unsigned)l1 << 16);
        pl.y = (unsigned)l2 | ((unsigned)l3 << 16);
        pl.z = (unsigned)l4 | ((unsigned)l5 << 16);
        pl.w = (unsigned)l6 | ((unsigned)l7 << 16);
        *(uint4*)&xl[(size_t)row*NC + d0] = pl;
    }
}

// ---------------- KNN stage 2: 3-term split-bf16 MFMA Gram + compacted dense top-16 ----------------
// BYTE-EXACT round-8 config (measured 179 us, VGPR 64, occ 43%): cap-64 BUF[32][65],
// sequential-cb SCAN_STEP (no total/fallback temporaries — R13's cap-32 variant cost
// +4 VGPRs and tipped the 64-reg wave-slot cliff), full 4096-col sweep, grid 512.
#define SCAN_STEP(CP, X2S, REFRESH) do { \
    float4 dd = *(const float4*)&DT[dtrd]; \
    float4 xx = *(const float4*)&(X2S)[slotl*4]; \
    int cb = 0; \
    { float d2 = fmaf(-2.f, dd.x, xx.x); bool p = d2 <= Trow; \
      unsigned long long bal = __ballot(p); unsigned grp = (unsigned)(bal >> grpsh) & 0xFFFFu; \
      if (p) BUF[srow][cb + __popc(grp & lowm)] = mkkey(d2, (CP) + slotl*4 + 0); \
      cb += __popc(grp); } \
    { float d2 = fmaf(-2.f, dd.y, xx.y); bool p = d2 <= Trow; \
      unsigned long long bal = __ballot(p); unsigned grp = (unsigned)(bal >> grpsh) & 0xFFFFu; \
      if (p) BUF[srow][cb + __popc(grp & lowm)] = mkkey(d2, (CP) + slotl*4 + 1); \
      cb += __popc(grp); } \
    { float d2 = fmaf(-2.f, dd.z, xx.z); bool p = d2 <= Trow; \
      unsigned long long bal = __ballot(p); unsigned grp = (unsigned)(bal >> grpsh) & 0xFFFFu; \
      if (p) BUF[srow][cb + __popc(grp & lowm)] = mkkey(d2, (CP) + slotl*4 + 2); \
      cb += __popc(grp); } \
    { float d2 = fmaf(-2.f, dd.w, xx.w); bool p = d2 <= Trow; \
      unsigned long long bal = __ballot(p); unsigned grp = (unsigned)(bal >> grpsh) & 0xFFFFu; \
      if (p) BUF[srow][cb + __popc(grp & lowm)] = mkkey(d2, (CP) + slotl*4 + 3); \
      cb += __popc(grp); } \
    _Pragma("unroll") \
    for (int r = 0; r < 4; ++r) { \
        int ii = r*16 + slotl; \
        if (ii < cb) { \
            unsigned long long k = BUF[srow][ii]; \
            if (k < K15) INSERT16K(k); \
        } \
    } \
    if (REFRESH) { \
        unsigned long long tk = K15; \
        _Pragma("unroll") \
        for (int off = 1; off < 16; off <<= 1) { \
            unsigned long long o = __shfl_xor(tk, off, 64); \
            tk = (o < tk) ? o : tk; \
        } \
        unsigned uu = (unsigned)(tk >> 32); \
        uu = (uu > 0xFF800000u) ? 0xFF800000u : uu; \
        uu = (uu & 0x80000000u) ? (uu ^ 0x80000000u) : ~uu; \
        Trow = __uint_as_float(uu); \
    } \
} while (0)

__global__ __launch_bounds__(512, 2) void knn2_kernel(const ushort* __restrict__ XHg,
                                                      const ushort* __restrict__ XLg,
                                                      const float* __restrict__ x2g,
                                                      int* __restrict__ idxout)
{
    __shared__ __align__(16) ushort XCH[64*128];        // 16 KB [c][d ^ ((c&7)<<3)]
    __shared__ __align__(16) ushort XCL[64*128];        // 16 KB
    __shared__ __align__(16) float  DT[32*64];          //  8 KB rotation swizzle
    __shared__ unsigned long long   BUF[32][65];        // 16.6 KB survivor buffers (cap 64)
    __shared__ __align__(16) float  X2T[2][64];         //  0.5 KB
    int tid = threadIdx.x;
    int lane = tid & 63, wave = tid >> 6;
    int xcd = blockIdx.x & 7, sub = blockIdx.x >> 3;    // grid 512
    int batch = xcd >> 1;
    int band = sub*2 + (xcd & 1);                       // 0..127
    const ushort* XHb = XHg + (size_t)batch*NN*NC;
    const ushort* XLb = XLg + (size_t)batch*NN*NC;
    const float*  x2b = x2g + (size_t)batch*NN;
    int r0 = band*32;

    int rowblk = wave & 1, colblk = wave >> 1;
    int dbase = (lane >> 4) * 8;
    int gr = r0 + rowblk*16 + (lane & 15);
    bf16x8 AH[4], AL[4];
#pragma unroll
    for (int ks = 0; ks < 4; ++ks) {
        AH[ks] = *(const bf16x8*)&XHb[(size_t)gr*NC + ks*32 + dbase];
        AL[ks] = *(const bf16x8*)&XLb[(size_t)gr*NC + ks*32 + dbase];
    }
    int cB = colblk*16 + (lane & 15);
    int colw = cB;

    int srow = tid >> 4, slotl = tid & 15;
    int grpsh = lane & 48;
    unsigned lowm = (1u << slotl) - 1u;
    int dtrd = srow*64 + ((slotl*4 + 4*srow) & 63);
    float Trow = INFINITY;
    DECL16K

    for (int t = 0; t < 64; ++t) {
        int c0 = t*64;
        __syncthreads();                                // MFMA(t-1) done: DT ready, XC free
        // stage hi+lo col tiles with XOR swizzle
#pragma unroll
        for (int i = 0; i < 2; ++i) {
            int qq = tid + 512*i;
            int c = qq >> 4, d8 = qq & 15;
            int widx = c*128 + ((d8*8) ^ ((c & 7) << 3));
            *(uint4*)&XCH[widx] = *(const uint4*)&XHb[(size_t)(c0 + c)*NC + d8*8];
            *(uint4*)&XCL[widx] = *(const uint4*)&XLb[(size_t)(c0 + c)*NC + d8*8];
        }
        if (tid < 64) X2T[t & 1][tid] = x2b[c0 + tid];
        if (t > 0) {
            const float* x2s = X2T[(t - 1) & 1];
            SCAN_STEP(c0 - 64, x2s, 1);
        }
        __syncthreads();                                // staging visible; DT free
        // MFMA: one 16x16 tile per wave, 3-term split-bf16 (hh + lh + hl), K=128
        f32x4 acc = {0.f, 0.f, 0.f, 0.f};
#pragma unroll
        for (int ks = 0; ks < 4; ++ks) {
            int bidx = cB*128 + ((ks*32 + dbase) ^ ((cB & 7) << 3));
            bf16x8 bh = *(const bf16x8*)&XCH[bidx];
            bf16x8 bl = *(const bf16x8*)&XCL[bidx];
            acc = __builtin_amdgcn_mfma_f32_16x16x32_bf16(AH[ks], bh, acc, 0, 0, 0);
            acc = __builtin_amdgcn_mfma_f32_16x16x32_bf16(AL[ks], bh, acc, 0, 0, 0);
            acc = __builtin_amdgcn_mfma_f32_16x16x32_bf16(AH[ks], bl, acc, 0, 0, 0);
        }
#pragma unroll
        for (int r2 = 0; r2 < 4; ++r2) {                // C/D: col=lane&15, row=(lane>>4)*4+reg
            int rA = rowblk*16 + (lane >> 4)*4 + r2;
            DT[rA*64 + (((colw & ~3) + 4*rA) & 63) + (colw & 3)] = acc[r2];
        }
    }
    __syncthreads();
    {   // scan last tile (t=63's DT), parity 63&1 = 1
        const float* x2s = X2T[1];
        SCAN_STEP(63*64, x2s, 0);
    }
    // per-row 16-lane pop-merge; emit final top-16 indices
    int grow = batch*NN + r0 + srow;
    for (int tt = 0; tt < 16; ++tt) {
        unsigned long long g = K0;
#pragma unroll
        for (int off = 1; off < 16; off <<= 1) {
            unsigned long long o = __shfl_xor(g, off, 64);
            g = (o < g) ? o : g;
        }
        bool win = (K0 == g);
        if (win) idxout[grow*16 + tt] = (int)(unsigned)(g & 0xFFFFFFFFull);
        POP16K(win);
    }
}

// ---------------- final fused LN / linear / LN / transpose ----------------
__global__ __launch_bounds__(256) void final_kernel(
    const float* __restrict__ tgt, const float* __restrict__ att,
    const float* __restrict__ Wl, const float* __restrict__ bl,
    const float* __restrict__ g0, const float* __restrict__ b0,
    const float* __restrict__ g1, const float* __restrict__ b1,
    float* __restrict__ outp)
{
    __shared__ float WL[128*128];
    int tid = threadIdx.x;
    for (int f = tid; f < 16384; f += 256) {
        int c = f >> 7, d = f & 127;
        WL[d*128 + (c ^ (d & 14))] = Wl[f];
    }
    __syncthreads();
    int lane = tid & 63, wave = tid >> 6;
    float2 gg0 = *(const float2*)&g0[2*lane];
    float2 bb0 = *(const float2*)&b0[2*lane];
    float2 gg1 = *(const float2*)&g1[2*lane];
    float2 bb1 = *(const float2*)&b1[2*lane];
    float2 bl2 = *(const float2*)&bl[2*lane];
    for (int it = 0; it < 4; ++it) {
        int row0 = blockIdx.x*64 + it*16 + wave*4;
        float2 tg[4];
        float lnx[4], lny[4];
#pragma unroll
        for (int r = 0; r < 4; ++r) {
            int row = row0 + r;
            tg[r] = *(const float2*)&tgt[row*128 + 2*lane];
            float2 at = *(const float2*)&att[row*128 + 2*lane];
            float ox = tg[r].x + at.x, oy = tg[r].y + at.y;
            float s = ox + oy;
#pragma unroll
            for (int off = 1; off < 64; off <<= 1) s += __shfl_xor(s, off, 64);
            float mu = s * (1.f/128.f);
            float dx = ox - mu, dy = oy - mu;
            float vv = fmaf(dx, dx, dy*dy);
#pragma unroll
            for (int off = 1; off < 64; off <<= 1) vv += __shfl_xor(vv, off, 64);
            float rstd = rsqrtf(vv * (1.f/128.f) + 1e-5f);
            lnx[r] = dx * rstd * gg0.x + bb0.x;
            lny[r] = dy * rstd * gg0.y + bb0.y;
        }
        float2 acc[4];
#pragma unroll
        for (int r = 0; r < 4; ++r) { acc[r].x = 0.f; acc[r].y = 0.f; }
#pragma unroll 8
        for (int dh = 0; dh < 64; ++dh) {
            int cidx = (2*lane) ^ ((2*dh) & 14);
            float2 wa = *(const float2*)&WL[(2*dh)*128 + cidx];
            float2 wb = *(const float2*)&WL[(2*dh+1)*128 + cidx];
#pragma unroll
            for (int r = 0; r < 4; ++r) {
                float xa = rl_f(lnx[r], dh);
                float xb = rl_f(lny[r], dh);
                acc[r].x = fmaf(xa, wa.x, acc[r].x);
                acc[r].y = fmaf(xa, wa.y, acc[r].y);
                acc[r].x = fmaf(xb, wb.x, acc[r].x);
                acc[r].y = fmaf(xb, wb.y, acc[r].y);
            }
        }
#pragma unroll
        for (int r = 0; r < 4; ++r) {
            int row = row0 + r;
            float zx = tg[r].x + acc[r].x + bl2.x;
            float zy = tg[r].y + acc[r].y + bl2.y;
            float s = zx + zy;
#pragma unroll
            for (int off = 1; off < 64; off <<= 1) s += __shfl_xor(s, off, 64);
            float mu = s * (1.f/128.f);
            float dx = zx - mu, dy = zy - mu;
            float vv = fmaf(dx, dx, dy*dy);
#pragma unroll
            for (int off = 1; off < 64; off <<= 1) vv += __shfl_xor(vv, off, 64);
            float rstd = rsqrtf(vv * (1.f/128.f) + 1e-5f);
            float2 res;
            res.x = dx * rstd * gg1.x + bb1.x;
            res.y = dy * rstd * gg1.y + bb1.y;
            int b = row >> 12, n = row & 4095;
            *(float2*)&outp[((size_t)n*NB + b)*128 + 2*lane] = res;
        }
    }
}

extern "C" void kernel_launch(void* const* d_in, const int* in_sizes, int n_in,
                              void* d_out, int out_size, void* d_ws, size_t ws_size,
                              hipStream_t stream)
{
    (void)in_sizes; (void)n_in; (void)out_size; (void)ws_size;
    const float* src = (const float*)d_in[0];
    const float* tgt = (const float*)d_in[1];
    const float* Wq0 = (const float*)d_in[2];
    const float* Wk0 = (const float*)d_in[3];
    const float* Wv0 = (const float*)d_in[4];
    const float* Wq1 = (const float*)d_in[5];
    const float* Wk1 = (const float*)d_in[6];
    const float* Wv1 = (const float*)d_in[7];
    const float* Wp0 = (const float*)d_in[8];
    const float* bp0 = (const float*)d_in[9];
    const float* Wp1 = (const float*)d_in[10];
    const float* bp1 = (const float*)d_in[11];
    const float* Wl  = (const float*)d_in[12];
    const float* bl  = (const float*)d_in[13];
    const float* g0  = (const float*)d_in[14];
    const float* b0  = (const float*)d_in[15];
    const float* g1  = (const float*)d_in[16];
    const float* b1  = (const float*)d_in[17];
    float* out = (float*)d_out;

    float* A0   = (float*)d_ws;                  // Ybase: A0..A4 contiguous
    float* A1   = A0 + 2097152;
    float* A2   = A1 + 2097152;
    float* A3   = A2 + 2097152;
    float* A4   = A3 + 2097152;
    float* OUT1 = A4 + 2097152;
    int*   IDX1 = (int*)(OUT1 + 2097152);
    int*   IDX2 = IDX1 + NROWS*16;
    float* X2G  = (float*)(IDX2 + NROWS*16);
    float* WKP0 = X2G + NROWS;
    float* BK0  = WKP0 + 384;
    float* WVP0 = BK0 + 128;
    float* BV0  = WVP0 + 384;
    float* WKD  = BV0 + 128;
    float* MV1  = WKD + 16384;
    float* WVD  = MV1 + 16384;
    float* BV1  = WVD + 16384;
    ushort* WSH = (ushort*)(BV1 + 128);          // 7 x 16384 bf16-hi weight slots
    ushort* WSL = WSH + 7*16384;                 // 7 x 16384 bf16-lo
    ushort* XH  = WSL + 7*16384;                 // 4 MB (tgt-split, then OUT1-split)
    ushort* XL  = XH + (size_t)NROWS*NC;         // 4 MB

    combo_small<<<dim3(2), dim3(512), 0, stream>>>(Wk0, Wv0, Wp0, bp0, WKP0, BK0, WVP0, BV0);
    combo_big<<<dim3(129), dim3(256), 0, stream>>>(Wk1, Wv1, Wp1, bp1, WKD, MV1, WVD, BV1);
    // weight slots: 0=Wq0 1=Wk0 2=Wv0 | 3=Wq1 4=WKD 5=WVD 6=MV1
    split7<<<dim3(64, 7), dim3(256), 0, stream>>>(Wq0, Wk0, Wv0, Wq1, WKD, WVD, MV1, WSH, WSL);
    srcproj<<<dim3(8192), dim3(256), 0, stream>>>(src, WKP0, WVP0, A3, A4);
    splitx<<<dim3(1024), dim3(256), 0, stream>>>(tgt, XH, XL);      // XH/XL = tgt split
    knn1_kernel<<<dim3(4096), dim3(256), 0, stream>>>(src, IDX1);
    // stage-1 GEMMs: A0 = tgt@Wq0^T ; A1 = tgt@Wk0^T - srcKp(A3) ; A2 = tgt@Wv0^T - srcVp(A4)
    gemm128<<<dim3(256, 3), dim3(256), 0, stream>>>(XH, XL, WSH, WSL, A3, A4, A0);
    attn_kernel<<<dim3(512), dim3(512), 0, stream>>>(A0, A1, A2, A4, BV0, IDX1, OUT1, X2G, XH, XL);
    knn2_kernel<<<dim3(512), dim3(512), 0, stream>>>(XH, XL, X2G, IDX2);
    // stage-2 GEMMs: A0 = Q1 ; A1 = GK2 ; A2 = GV2 ; A3 = BASE2 (X@MV1^T)
    gemm128<<<dim3(256, 4), dim3(256), 0, stream>>>(XH, XL, WSH + 3*16384, WSL + 3*16384,
                                                    nullptr, nullptr, A0);
    attn_kernel<<<dim3(512), dim3(512), 0, stream>>>(A0, A1, A2, A3, BV1, IDX2, OUT1, nullptr, nullptr, nullptr);
    final_kernel<<<dim3(256), dim3(256), 0, stream>>>(tgt, OUT1, Wl, bl, g0, b0, g1, b1, out);
}